// Round 1
// baseline (4515.899 us; speedup 1.0000x reference)
//
#include <hip/hip_runtime.h>
#include <math.h>

#define N_NODES 100000
#define N_EDGES 1600000
#define DIM     128
#define NCLS    40

// ---------------------------------------------------------------- degree
__global__ __launch_bounds__(256) void deg_count(const int* __restrict__ ei,
                                                 float* __restrict__ deg) {
    int e = blockIdx.x * 256 + threadIdx.x;
    if (e < N_EDGES) atomicAdd(&deg[ei[N_EDGES + e]], 1.0f);
}

__global__ __launch_bounds__(256) void finalize_dinv(float* __restrict__ deg) {
    int n = blockIdx.x * 256 + threadIdx.x;
    if (n < N_NODES) deg[n] = rsqrtf(deg[n] + 1.0f);
}

// ---------------------------------------------------------------- GEMM h = X @ W  (X: N x 128, W: 128 x 128)
// 32 rows per block, W fully in LDS, 4x4 register tile per thread.
__global__ __launch_bounds__(256) void gemm128(const float* __restrict__ X,
                                               const float* __restrict__ W,
                                               float* __restrict__ H) {
    __shared__ float wlds[128 * 128];   // 64 KB
    __shared__ float xt[128 * 32];      // transposed x tile: xt[k*32 + r], 16 KB
    const int tid  = threadIdx.x;
    const int row0 = blockIdx.x * 32;

    const float4* W4  = (const float4*)W;
    float4*       wl4 = (float4*)wlds;
#pragma unroll
    for (int i = 0; i < 16; ++i) wl4[tid + i * 256] = W4[tid + i * 256];

#pragma unroll
    for (int i = 0; i < 4; ++i) {
        int idx = tid + i * 256;         // 0..1023 float4s
        int r   = idx >> 5;              // row 0..31
        int c4  = idx & 31;              // float4 col
        float4 v = ((const float4*)(X + (size_t)(row0 + r) * DIM))[c4];
        int c = c4 * 4;
        xt[(c + 0) * 32 + r] = v.x;
        xt[(c + 1) * 32 + r] = v.y;
        xt[(c + 2) * 32 + r] = v.z;
        xt[(c + 3) * 32 + r] = v.w;
    }
    __syncthreads();

    const int tr = tid >> 5;   // 0..7  -> rows tr*4..tr*4+3
    const int tc = tid & 31;   // 0..31 -> cols tc*4..tc*4+3
    float acc[4][4] = {};
#pragma unroll 8
    for (int k = 0; k < 128; ++k) {
        float4 a = *(const float4*)(xt + k * 32 + tr * 4);
        float4 b = *(const float4*)(wlds + k * 128 + tc * 4);
        acc[0][0] += a.x * b.x; acc[0][1] += a.x * b.y; acc[0][2] += a.x * b.z; acc[0][3] += a.x * b.w;
        acc[1][0] += a.y * b.x; acc[1][1] += a.y * b.y; acc[1][2] += a.y * b.z; acc[1][3] += a.y * b.w;
        acc[2][0] += a.z * b.x; acc[2][1] += a.z * b.y; acc[2][2] += a.z * b.z; acc[2][3] += a.z * b.w;
        acc[3][0] += a.w * b.x; acc[3][1] += a.w * b.y; acc[3][2] += a.w * b.z; acc[3][3] += a.w * b.w;
    }
#pragma unroll
    for (int i = 0; i < 4; ++i) {
        float4 o = make_float4(acc[i][0], acc[i][1], acc[i][2], acc[i][3]);
        ((float4*)(H + (size_t)(row0 + tr * 4 + i) * DIM))[tc] = o;
    }
}

// ---------------------------------------------------------------- agg = h * dinv^2 + bias   (also zero-init for scatter)
__global__ __launch_bounds__(256) void init_agg(const float* __restrict__ h,
                                                const float* __restrict__ bias,
                                                const float* __restrict__ dinv,
                                                float* __restrict__ agg) {
    int idx  = blockIdx.x * 256 + threadIdx.x;  // float4 index, N*32 total
    int node = idx >> 5;
    int c4   = idx & 31;
    float dv = dinv[node];
    float d2 = dv * dv;
    float4 hv = ((const float4*)h)[idx];
    float4 bv = ((const float4*)bias)[c4];
    ((float4*)agg)[idx] = make_float4(hv.x * d2 + bv.x, hv.y * d2 + bv.y,
                                      hv.z * d2 + bv.z, hv.w * d2 + bv.w);
}

// ---------------------------------------------------------------- scatter: agg[dst] += h[src] * dinv[s]*dinv[d]
__global__ __launch_bounds__(256) void scatter_edges(const int* __restrict__ ei,
                                                     const float* __restrict__ h,
                                                     float* __restrict__ agg,
                                                     const float* __restrict__ dinv) {
    int e    = blockIdx.x * 4 + (threadIdx.x >> 6);  // one wave per edge
    int lane = threadIdx.x & 63;
    int s = ei[e];
    int d = ei[N_EDGES + e];
    float w = dinv[s] * dinv[d];
    float2 v = ((const float2*)(h + (size_t)s * DIM))[lane];
    float* dst = agg + (size_t)d * DIM + lane * 2;
    atomicAdd(dst,     v.x * w);
    atomicAdd(dst + 1, v.y * w);
}

// ---------------------------------------------------------------- LayerNorm + ELU (+ residual), in place, one wave per node
__global__ __launch_bounds__(256) void ln_elu_res(float* __restrict__ io,
                                                  const float* __restrict__ xin,
                                                  const float* __restrict__ g,
                                                  const float* __restrict__ be) {
    int node = blockIdx.x * 4 + (threadIdx.x >> 6);
    int lane = threadIdx.x & 63;
    float2 v = ((float2*)(io + (size_t)node * DIM))[lane];
    float s1 = v.x + v.y;
    float s2 = v.x * v.x + v.y * v.y;
#pragma unroll
    for (int m = 1; m < 64; m <<= 1) {
        s1 += __shfl_xor(s1, m, 64);
        s2 += __shfl_xor(s2, m, 64);
    }
    float mean = s1 * (1.0f / 128.0f);
    float var  = s2 * (1.0f / 128.0f) - mean * mean;
    float r    = rsqrtf(var + 1e-5f);
    float2 gg = ((const float2*)g)[lane];
    float2 bb = ((const float2*)be)[lane];
    float a0 = (v.x - mean) * r * gg.x + bb.x;
    float a1 = (v.y - mean) * r * gg.y + bb.y;
    a0 = a0 > 0.0f ? a0 : expm1f(a0);
    a1 = a1 > 0.0f ? a1 : expm1f(a1);
    if (xin) {
        float2 xi = ((const float2*)(xin + (size_t)node * DIM))[lane];
        a0 += xi.x;
        a1 += xi.y;
    }
    ((float2*)(io + (size_t)node * DIM))[lane] = make_float2(a0, a1);
}

// ---------------------------------------------------------------- classifier: out = x @ Wc + bc   (Wc: 128 x 40)
__global__ __launch_bounds__(256) void classifier(const float* __restrict__ X,
                                                  const float* __restrict__ Wc,
                                                  const float* __restrict__ bc,
                                                  float* __restrict__ out) {
    __shared__ float wc[DIM * NCLS];    // 20 KB
    __shared__ float xs[64 * DIM];      // 32 KB
    __shared__ float bcs[NCLS];
    const int tid  = threadIdx.x;
    const int row0 = blockIdx.x * 64;

#pragma unroll
    for (int i = 0; i < 20; ++i) wc[tid + i * 256] = Wc[tid + i * 256];
    if (tid < NCLS) bcs[tid] = bc[tid];

#pragma unroll
    for (int i = 0; i < 8; ++i) {
        int idx = tid + i * 256;        // float4 index over 64*32
        int r   = idx >> 5;
        int c4  = idx & 31;
        int row = row0 + r;
        float4 v = (row < N_NODES)
                       ? ((const float4*)(X + (size_t)row * DIM))[c4]
                       : make_float4(0.f, 0.f, 0.f, 0.f);
        ((float4*)(xs + r * DIM))[c4] = v;
    }
    __syncthreads();

#pragma unroll
    for (int j = 0; j < 10; ++j) {
        int idx = tid + j * 256;        // 0..2559
        int r   = idx / NCLS;
        int c   = idx % NCLS;
        int row = row0 + r;
        if (row < N_NODES) {
            float acc = bcs[c];
#pragma unroll 8
            for (int k = 0; k < DIM; ++k) acc += xs[r * DIM + k] * wc[k * NCLS + c];
            out[(size_t)row * NCLS + c] = acc;
        }
    }
}

// ---------------------------------------------------------------- launch
extern "C" void kernel_launch(void* const* d_in, const int* in_sizes, int n_in,
                              void* d_out, int out_size, void* d_ws, size_t ws_size,
                              hipStream_t stream) {
    const float* x  = (const float*)d_in[0];
    const int*   ei = (const int*)d_in[1];
    const float* W[3]  = {(const float*)d_in[2], (const float*)d_in[6], (const float*)d_in[10]};
    const float* b[3]  = {(const float*)d_in[3], (const float*)d_in[7], (const float*)d_in[11]};
    const float* g[3]  = {(const float*)d_in[4], (const float*)d_in[8], (const float*)d_in[12]};
    const float* be[3] = {(const float*)d_in[5], (const float*)d_in[9], (const float*)d_in[13]};
    const float* Wc = (const float*)d_in[14];
    const float* bc = (const float*)d_in[15];
    float* out = (float*)d_out;

    char*  ws   = (char*)d_ws;
    float* dinv = (float*)ws;                         // N floats (deg then dinv)
    float* A    = (float*)(ws + 400128);              // N*128 fp32, 16B aligned
    float* B    = A + (size_t)N_NODES * DIM;
    float* C    = B + (size_t)N_NODES * DIM;

    // degrees (with self-loop) -> dinv
    hipMemsetAsync(dinv, 0, N_NODES * sizeof(float), stream);
    deg_count<<<(N_EDGES + 255) / 256, 256, 0, stream>>>(ei, dinv);
    finalize_dinv<<<(N_NODES + 255) / 256, 256, 0, stream>>>(dinv);

    const int gemm_grid = N_NODES / 32;       // 3125
    const int init_grid = N_NODES * 32 / 256; // 12500
    const int scat_grid = N_EDGES / 4;        // 400000
    const int ln_grid   = N_NODES / 4;        // 25000

    // layer 0: x_in = x, h = B, agg/out = C
    gemm128<<<gemm_grid, 256, 0, stream>>>(x, W[0], B);
    init_agg<<<init_grid, 256, 0, stream>>>(B, b[0], dinv, C);
    scatter_edges<<<scat_grid, 256, 0, stream>>>(ei, B, C, dinv);
    ln_elu_res<<<ln_grid, 256, 0, stream>>>(C, nullptr, g[0], be[0]);

    // layer 1: x_in = C, h = B, agg/out = A
    gemm128<<<gemm_grid, 256, 0, stream>>>(C, W[1], B);
    init_agg<<<init_grid, 256, 0, stream>>>(B, b[1], dinv, A);
    scatter_edges<<<scat_grid, 256, 0, stream>>>(ei, B, A, dinv);
    ln_elu_res<<<ln_grid, 256, 0, stream>>>(A, C, g[1], be[1]);

    // layer 2: x_in = A, h = B, agg/out = C
    gemm128<<<gemm_grid, 256, 0, stream>>>(A, W[2], B);
    init_agg<<<init_grid, 256, 0, stream>>>(B, b[2], dinv, C);
    scatter_edges<<<scat_grid, 256, 0, stream>>>(ei, B, C, dinv);
    ln_elu_res<<<ln_grid, 256, 0, stream>>>(C, A, g[2], be[2]);

    classifier<<<(N_NODES + 63) / 64, 256, 0, stream>>>(C, Wc, bc, out);
}

// Round 2
// 933.029 us; speedup vs baseline: 4.8400x; 4.8400x over previous
//
#include <hip/hip_runtime.h>
#include <math.h>

#define N_NODES 100000
#define N_EDGES 1600000
#define DIM     128
#define NCLS    40
#define SCAN_BLOCKS 98   // ceil(100000/1024)

// ---------------------------------------------------------------- degree (int)
__global__ __launch_bounds__(256) void deg_count(const int* __restrict__ ei,
                                                 int* __restrict__ degi) {
    int e = blockIdx.x * 256 + threadIdx.x;
    if (e < N_EDGES) atomicAdd(&degi[ei[N_EDGES + e]], 1);
}

__global__ __launch_bounds__(256) void finalize_dinv(const int* __restrict__ degi,
                                                     float* __restrict__ dinv) {
    int n = blockIdx.x * 256 + threadIdx.x;
    if (n < N_NODES) dinv[n] = rsqrtf((float)degi[n] + 1.0f);
}

// ---------------------------------------------------------------- scan (exclusive) over degi -> rowptr
__global__ __launch_bounds__(256) void scan1(const int* __restrict__ degi,
                                             int* __restrict__ rowptr,
                                             int* __restrict__ bsums) {
    __shared__ int sums[256];
    int t    = threadIdx.x;
    int base = blockIdx.x * 1024 + t * 4;
    int v[4], s = 0;
#pragma unroll
    for (int i = 0; i < 4; ++i) {
        int idx = base + i;
        v[i] = (idx < N_NODES) ? degi[idx] : 0;
        s += v[i];
    }
    sums[t] = s;
    __syncthreads();
    for (int off = 1; off < 256; off <<= 1) {
        int x = (t >= off) ? sums[t - off] : 0;
        __syncthreads();
        sums[t] += x;
        __syncthreads();
    }
    int run = (t == 0) ? 0 : sums[t - 1];
#pragma unroll
    for (int i = 0; i < 4; ++i) {
        int idx = base + i;
        if (idx < N_NODES) rowptr[idx] = run;
        run += v[i];
    }
    if (t == 255) bsums[blockIdx.x] = sums[255];
}

__global__ __launch_bounds__(128) void scan2(int* __restrict__ bsums) {
    __shared__ int s[128];
    int t = threadIdx.x;
    s[t] = (t < SCAN_BLOCKS) ? bsums[t] : 0;
    __syncthreads();
    for (int off = 1; off < 128; off <<= 1) {
        int x = (t >= off) ? s[t - off] : 0;
        __syncthreads();
        s[t] += x;
        __syncthreads();
    }
    if (t < SCAN_BLOCKS) bsums[t] = (t == 0) ? 0 : s[t - 1];
}

__global__ __launch_bounds__(256) void scan3(int* __restrict__ rowptr,
                                             int* __restrict__ ctr,
                                             const int* __restrict__ bsums) {
    int idx = blockIdx.x * 256 + threadIdx.x;
    if (idx < N_NODES) {
        int v = rowptr[idx] + bsums[idx >> 10];
        rowptr[idx] = v;
        ctr[idx]    = v;
    }
    if (idx == 0) rowptr[N_NODES] = N_EDGES;
}

// ---------------------------------------------------------------- fill CSR (by dst), precompute edge weights
__global__ __launch_bounds__(256) void fill_csr(const int* __restrict__ ei,
                                                const float* __restrict__ dinv,
                                                int* __restrict__ ctr,
                                                int* __restrict__ esrc,
                                                float* __restrict__ ew) {
    int e = blockIdx.x * 256 + threadIdx.x;
    if (e < N_EDGES) {
        int s = ei[e];
        int d = ei[N_EDGES + e];
        int pos = atomicAdd(&ctr[d], 1);
        esrc[pos] = s;
        ew[pos]   = dinv[s] * dinv[d];
    }
}

// ---------------------------------------------------------------- GEMM h = X @ W  (X: N x 128, W: 128 x 128)
__global__ __launch_bounds__(256) void gemm128(const float* __restrict__ X,
                                               const float* __restrict__ W,
                                               float* __restrict__ H) {
    __shared__ float wlds[128 * 128];
    __shared__ float xt[128 * 32];
    const int tid  = threadIdx.x;
    const int row0 = blockIdx.x * 32;

    const float4* W4  = (const float4*)W;
    float4*       wl4 = (float4*)wlds;
#pragma unroll
    for (int i = 0; i < 16; ++i) wl4[tid + i * 256] = W4[tid + i * 256];

#pragma unroll
    for (int i = 0; i < 4; ++i) {
        int idx = tid + i * 256;
        int r   = idx >> 5;
        int c4  = idx & 31;
        float4 v = ((const float4*)(X + (size_t)(row0 + r) * DIM))[c4];
        int c = c4 * 4;
        xt[(c + 0) * 32 + r] = v.x;
        xt[(c + 1) * 32 + r] = v.y;
        xt[(c + 2) * 32 + r] = v.z;
        xt[(c + 3) * 32 + r] = v.w;
    }
    __syncthreads();

    const int tr = tid >> 5;
    const int tc = tid & 31;
    float acc[4][4] = {};
#pragma unroll 8
    for (int k = 0; k < 128; ++k) {
        float4 a = *(const float4*)(xt + k * 32 + tr * 4);
        float4 b = *(const float4*)(wlds + k * 128 + tc * 4);
        acc[0][0] += a.x * b.x; acc[0][1] += a.x * b.y; acc[0][2] += a.x * b.z; acc[0][3] += a.x * b.w;
        acc[1][0] += a.y * b.x; acc[1][1] += a.y * b.y; acc[1][2] += a.y * b.z; acc[1][3] += a.y * b.w;
        acc[2][0] += a.z * b.x; acc[2][1] += a.z * b.y; acc[2][2] += a.z * b.z; acc[2][3] += a.z * b.w;
        acc[3][0] += a.w * b.x; acc[3][1] += a.w * b.y; acc[3][2] += a.w * b.z; acc[3][3] += a.w * b.w;
    }
#pragma unroll
    for (int i = 0; i < 4; ++i) {
        float4 o = make_float4(acc[i][0], acc[i][1], acc[i][2], acc[i][3]);
        ((float4*)(H + (size_t)(row0 + tr * 4 + i) * DIM))[tc] = o;
    }
}

// ---------------------------------------------------------------- fused gather-aggregate + LN + ELU (+ residual)
// out[node] = act(LN(sum_{e in CSR[node]} h[esrc[e]]*ew[e] + h[node]*dinv^2 + bias)) [+ xin[node]]
__global__ __launch_bounds__(256) void agg_ln(const float* __restrict__ h,
                                              const float* __restrict__ xin,
                                              const float* __restrict__ dinv,
                                              const float* __restrict__ bias,
                                              const float* __restrict__ g,
                                              const float* __restrict__ be,
                                              const int* __restrict__ rowptr,
                                              const int* __restrict__ esrc,
                                              const float* __restrict__ ew,
                                              float* __restrict__ out) {
    int node = blockIdx.x * 4 + (threadIdx.x >> 6);
    int lane = threadIdx.x & 63;
    int beg = rowptr[node];
    int end = rowptr[node + 1];

    float dv = dinv[node];
    float d2 = dv * dv;
    float2 hv = ((const float2*)(h + (size_t)node * DIM))[lane];
    float2 bv = ((const float2*)bias)[lane];
    float ax = hv.x * d2 + bv.x;
    float ay = hv.y * d2 + bv.y;

    for (int e0 = beg; e0 < end; e0 += 64) {
        int cnt = end - e0;
        if (cnt > 64) cnt = 64;
        int   sv = 0;
        float wv = 0.0f;
        if (lane < cnt) {
            sv = esrc[e0 + lane];
            wv = ew[e0 + lane];
        }
        int j = 0;
        for (; j + 1 < cnt; j += 2) {
            int   s0 = __shfl(sv, j, 64);
            float w0 = __shfl(wv, j, 64);
            int   s1 = __shfl(sv, j + 1, 64);
            float w1 = __shfl(wv, j + 1, 64);
            float2 v0 = ((const float2*)(h + (size_t)s0 * DIM))[lane];
            float2 v1 = ((const float2*)(h + (size_t)s1 * DIM))[lane];
            ax += v0.x * w0 + v1.x * w1;
            ay += v0.y * w0 + v1.y * w1;
        }
        if (j < cnt) {
            int   s0 = __shfl(sv, j, 64);
            float w0 = __shfl(wv, j, 64);
            float2 v0 = ((const float2*)(h + (size_t)s0 * DIM))[lane];
            ax += v0.x * w0;
            ay += v0.y * w0;
        }
    }

    // LayerNorm across 128 dims (wave-wide)
    float s1 = ax + ay;
    float s2 = ax * ax + ay * ay;
#pragma unroll
    for (int m = 1; m < 64; m <<= 1) {
        s1 += __shfl_xor(s1, m, 64);
        s2 += __shfl_xor(s2, m, 64);
    }
    float mean = s1 * (1.0f / 128.0f);
    float var  = s2 * (1.0f / 128.0f) - mean * mean;
    float r    = rsqrtf(var + 1e-5f);
    float2 gg = ((const float2*)g)[lane];
    float2 bb = ((const float2*)be)[lane];
    float a0 = (ax - mean) * r * gg.x + bb.x;
    float a1 = (ay - mean) * r * gg.y + bb.y;
    a0 = a0 > 0.0f ? a0 : expm1f(a0);
    a1 = a1 > 0.0f ? a1 : expm1f(a1);
    if (xin) {
        float2 xi = ((const float2*)(xin + (size_t)node * DIM))[lane];
        a0 += xi.x;
        a1 += xi.y;
    }
    ((float2*)(out + (size_t)node * DIM))[lane] = make_float2(a0, a1);
}

// ---------------------------------------------------------------- classifier: out = x @ Wc + bc
__global__ __launch_bounds__(256) void classifier(const float* __restrict__ X,
                                                  const float* __restrict__ Wc,
                                                  const float* __restrict__ bc,
                                                  float* __restrict__ out) {
    __shared__ float wc[DIM * NCLS];
    __shared__ float xs[64 * DIM];
    __shared__ float bcs[NCLS];
    const int tid  = threadIdx.x;
    const int row0 = blockIdx.x * 64;

#pragma unroll
    for (int i = 0; i < 20; ++i) wc[tid + i * 256] = Wc[tid + i * 256];
    if (tid < NCLS) bcs[tid] = bc[tid];

#pragma unroll
    for (int i = 0; i < 8; ++i) {
        int idx = tid + i * 256;
        int r   = idx >> 5;
        int c4  = idx & 31;
        int row = row0 + r;
        float4 v = (row < N_NODES)
                       ? ((const float4*)(X + (size_t)row * DIM))[c4]
                       : make_float4(0.f, 0.f, 0.f, 0.f);
        ((float4*)(xs + r * DIM))[c4] = v;
    }
    __syncthreads();

#pragma unroll
    for (int j = 0; j < 10; ++j) {
        int idx = tid + j * 256;
        int r   = idx / NCLS;
        int c   = idx % NCLS;
        int row = row0 + r;
        if (row < N_NODES) {
            float acc = bcs[c];
#pragma unroll 8
            for (int k = 0; k < DIM; ++k) acc += xs[r * DIM + k] * wc[k * NCLS + c];
            out[(size_t)row * NCLS + c] = acc;
        }
    }
}

// ---------------------------------------------------------------- launch
extern "C" void kernel_launch(void* const* d_in, const int* in_sizes, int n_in,
                              void* d_out, int out_size, void* d_ws, size_t ws_size,
                              hipStream_t stream) {
    const float* x  = (const float*)d_in[0];
    const int*   ei = (const int*)d_in[1];
    const float* W[3]  = {(const float*)d_in[2], (const float*)d_in[6], (const float*)d_in[10]};
    const float* b[3]  = {(const float*)d_in[3], (const float*)d_in[7], (const float*)d_in[11]};
    const float* g[3]  = {(const float*)d_in[4], (const float*)d_in[8], (const float*)d_in[12]};
    const float* be[3] = {(const float*)d_in[5], (const float*)d_in[9], (const float*)d_in[13]};
    const float* Wc = (const float*)d_in[14];
    const float* bc = (const float*)d_in[15];
    float* out = (float*)d_out;

    char* ws = (char*)d_ws;
    const size_t NP = 400128;  // padded N*4 bytes
    float* dinv   = (float*)(ws);
    int*   degi   = (int*)  (ws + NP);
    int*   rowptr = (int*)  (ws + 2 * NP);
    int*   ctr    = (int*)  (ws + 3 * NP);
    int*   bsums  = (int*)  (ws + 4 * NP);
    int*   esrc   = (int*)  (ws + 4 * NP + 512);
    float* ew     = (float*)(ws + 4 * NP + 512 + (size_t)N_EDGES * 4);
    float* A      = (float*)(ws + 4 * NP + 512 + (size_t)N_EDGES * 8);
    float* B      = A + (size_t)N_NODES * DIM;
    float* C      = B + (size_t)N_NODES * DIM;

    // ---- CSR build ----
    hipMemsetAsync(degi, 0, N_NODES * sizeof(int), stream);
    deg_count<<<(N_EDGES + 255) / 256, 256, 0, stream>>>(ei, degi);
    finalize_dinv<<<(N_NODES + 255) / 256, 256, 0, stream>>>(degi, dinv);
    scan1<<<SCAN_BLOCKS, 256, 0, stream>>>(degi, rowptr, bsums);
    scan2<<<1, 128, 0, stream>>>(bsums);
    scan3<<<SCAN_BLOCKS * 4, 256, 0, stream>>>(rowptr, ctr, bsums);
    fill_csr<<<(N_EDGES + 255) / 256, 256, 0, stream>>>(ei, dinv, ctr, esrc, ew);

    const int gemm_grid = N_NODES / 32;  // 3125
    const int agg_grid  = N_NODES / 4;   // 25000

    // layer 0: x_in = x (no residual), h = B, out = C
    gemm128<<<gemm_grid, 256, 0, stream>>>(x, W[0], B);
    agg_ln<<<agg_grid, 256, 0, stream>>>(B, nullptr, dinv, b[0], g[0], be[0], rowptr, esrc, ew, C);

    // layer 1: x_in = C, h = B, out = A
    gemm128<<<gemm_grid, 256, 0, stream>>>(C, W[1], B);
    agg_ln<<<agg_grid, 256, 0, stream>>>(B, C, dinv, b[1], g[1], be[1], rowptr, esrc, ew, A);

    // layer 2: x_in = A, h = B, out = C
    gemm128<<<gemm_grid, 256, 0, stream>>>(A, W[2], B);
    agg_ln<<<agg_grid, 256, 0, stream>>>(B, A, dinv, b[2], g[2], be[2], rowptr, esrc, ew, C);

    classifier<<<(N_NODES + 63) / 64, 256, 0, stream>>>(C, Wc, bc, out);
}

// Round 3
// 772.026 us; speedup vs baseline: 5.8494x; 1.2085x over previous
//
#include <hip/hip_runtime.h>
#include <math.h>

#define N_NODES 100000
#define N_EDGES 1600000
#define DIM     128
#define NCLS    40
#define SCAN_BLOCKS 98   // ceil(100000/1024)

// bf16 helpers (manual RNE; bf16->f32 is a shift)
__device__ inline unsigned short bf16r(float f) {
    unsigned u = __float_as_uint(f);
    unsigned r = (u + 0x7fffu + ((u >> 16) & 1u)) >> 16;
    return (unsigned short)r;
}
__device__ inline unsigned pack_bf2(float lo, float hi) {
    return (unsigned)bf16r(lo) | ((unsigned)bf16r(hi) << 16);
}
__device__ inline float bf_lo(unsigned v) { return __uint_as_float(v << 16); }
__device__ inline float bf_hi(unsigned v) { return __uint_as_float(v & 0xffff0000u); }

// ---------------------------------------------------------------- degree (int)
__global__ __launch_bounds__(256) void deg_count(const int* __restrict__ ei,
                                                 int* __restrict__ degi) {
    int e = blockIdx.x * 256 + threadIdx.x;
    if (e < N_EDGES) atomicAdd(&degi[ei[N_EDGES + e]], 1);
}

__global__ __launch_bounds__(256) void finalize_dinv(const int* __restrict__ degi,
                                                     float* __restrict__ dinv) {
    int n = blockIdx.x * 256 + threadIdx.x;
    if (n < N_NODES) dinv[n] = rsqrtf((float)degi[n] + 1.0f);
}

// ---------------------------------------------------------------- scan (exclusive) over degi -> rowptr
__global__ __launch_bounds__(256) void scan1(const int* __restrict__ degi,
                                             int* __restrict__ rowptr,
                                             int* __restrict__ bsums) {
    __shared__ int sums[256];
    int t    = threadIdx.x;
    int base = blockIdx.x * 1024 + t * 4;
    int v[4], s = 0;
#pragma unroll
    for (int i = 0; i < 4; ++i) {
        int idx = base + i;
        v[i] = (idx < N_NODES) ? degi[idx] : 0;
        s += v[i];
    }
    sums[t] = s;
    __syncthreads();
    for (int off = 1; off < 256; off <<= 1) {
        int x = (t >= off) ? sums[t - off] : 0;
        __syncthreads();
        sums[t] += x;
        __syncthreads();
    }
    int run = (t == 0) ? 0 : sums[t - 1];
#pragma unroll
    for (int i = 0; i < 4; ++i) {
        int idx = base + i;
        if (idx < N_NODES) rowptr[idx] = run;
        run += v[i];
    }
    if (t == 255) bsums[blockIdx.x] = sums[255];
}

__global__ __launch_bounds__(128) void scan2(int* __restrict__ bsums) {
    __shared__ int s[128];
    int t = threadIdx.x;
    s[t] = (t < SCAN_BLOCKS) ? bsums[t] : 0;
    __syncthreads();
    for (int off = 1; off < 128; off <<= 1) {
        int x = (t >= off) ? s[t - off] : 0;
        __syncthreads();
        s[t] += x;
        __syncthreads();
    }
    if (t < SCAN_BLOCKS) bsums[t] = (t == 0) ? 0 : s[t - 1];
}

__global__ __launch_bounds__(256) void scan3(int* __restrict__ rowptr,
                                             int* __restrict__ ctr,
                                             const int* __restrict__ bsums) {
    int idx = blockIdx.x * 256 + threadIdx.x;
    if (idx < N_NODES) {
        int v = rowptr[idx] + bsums[idx >> 10];
        rowptr[idx] = v;
        ctr[idx]    = v;
    }
    if (idx == 0) rowptr[N_NODES] = N_EDGES;
}

// ---------------------------------------------------------------- fill CSR (by dst), interleaved (src, weight)
__global__ __launch_bounds__(256) void fill_csr(const int* __restrict__ ei,
                                                const float* __restrict__ dinv,
                                                int* __restrict__ ctr,
                                                int2* __restrict__ rec) {
    int e = blockIdx.x * 256 + threadIdx.x;
    if (e < N_EDGES) {
        int s = ei[e];
        int d = ei[N_EDGES + e];
        int pos = atomicAdd(&ctr[d], 1);
        rec[pos] = make_int2(s, __float_as_int(dinv[s] * dinv[d]));
    }
}

// ---------------------------------------------------------------- GEMM h = X @ W  (X: N x 128, W: 128 x 128) -> bf16
// 128 rows/block, 256 threads, 8x8 register tile each. LDS: W 64KB + X^T 67.6KB.
__global__ __launch_bounds__(256) void gemm128(const float* __restrict__ X,
                                               const float* __restrict__ W,
                                               unsigned short* __restrict__ H) {
    __shared__ float wlds[128 * 128];    // row-major [k][c]
    __shared__ float xt[128 * 132];      // transposed [k][r], stride 132
    const int tid  = threadIdx.x;
    const int row0 = blockIdx.x * 128;

    const float4* W4  = (const float4*)W;
    float4*       wl4 = (float4*)wlds;
#pragma unroll
    for (int i = 0; i < 16; ++i) wl4[tid + i * 256] = W4[tid + i * 256];

    // stage X transposed: bank-balanced mapping (c4l=idx&3, r=(idx>>2)&127, c4h=idx>>9)
#pragma unroll
    for (int i = 0; i < 16; ++i) {
        int idx = tid + i * 256;             // 0..4095 float4s
        int c4l = idx & 3;
        int r   = (idx >> 2) & 127;
        int c4h = idx >> 9;                  // 0..7
        int c4  = c4h * 4 + c4l;
        int row = row0 + r;
        if (row >= N_NODES) row = N_NODES - 1;   // clamp (result unused)
        float4 v = ((const float4*)(X + (size_t)row * DIM))[c4];
        int c = c4 * 4;
        xt[(c + 0) * 132 + r] = v.x;
        xt[(c + 1) * 132 + r] = v.y;
        xt[(c + 2) * 132 + r] = v.z;
        xt[(c + 3) * 132 + r] = v.w;
    }
    __syncthreads();

    const int tr = tid >> 4;   // 0..15 -> rows tr*8..tr*8+7
    const int tc = tid & 15;   // 0..15 -> cols tc*8..tc*8+7
    const float* ap = xt + tr * 8;
    const float* bp = wlds + tc * 8;
    float acc[8][8] = {};
#pragma unroll 4
    for (int k = 0; k < 128; ++k) {
        float4 a0 = *(const float4*)(ap + k * 132);
        float4 a1 = *(const float4*)(ap + k * 132 + 4);
        float4 b0 = *(const float4*)(bp + k * 128);
        float4 b1 = *(const float4*)(bp + k * 128 + 4);
        float av[8] = {a0.x, a0.y, a0.z, a0.w, a1.x, a1.y, a1.z, a1.w};
        float bv[8] = {b0.x, b0.y, b0.z, b0.w, b1.x, b1.y, b1.z, b1.w};
#pragma unroll
        for (int i = 0; i < 8; ++i)
#pragma unroll
            for (int j = 0; j < 8; ++j) acc[i][j] += av[i] * bv[j];
    }

#pragma unroll
    for (int i = 0; i < 8; ++i) {
        int row = row0 + tr * 8 + i;
        if (row < N_NODES) {
            int4 o = make_int4((int)pack_bf2(acc[i][0], acc[i][1]),
                               (int)pack_bf2(acc[i][2], acc[i][3]),
                               (int)pack_bf2(acc[i][4], acc[i][5]),
                               (int)pack_bf2(acc[i][6], acc[i][7]));
            *(int4*)(H + (size_t)row * DIM + tc * 8) = o;
        }
    }
}

// ---------------------------------------------------------------- fused gather-aggregate + LN + ELU (+ residual)
// h is bf16 (2 cols per lane-word). out = act(LN(sum_e h[src]*w + h[node]*dinv^2 + bias)) [+ xin]
__global__ __launch_bounds__(256) void agg_ln(const unsigned short* __restrict__ Hb,
                                              const float* __restrict__ xin,
                                              const float* __restrict__ dinv,
                                              const float* __restrict__ bias,
                                              const float* __restrict__ g,
                                              const float* __restrict__ be,
                                              const int* __restrict__ rowptr,
                                              const int2* __restrict__ rec,
                                              float* __restrict__ out) {
    int node = blockIdx.x * 4 + (threadIdx.x >> 6);
    int lane = threadIdx.x & 63;
    int beg = rowptr[node];
    int end = rowptr[node + 1];

    float dv = dinv[node];
    float d2 = dv * dv;
    unsigned hv = ((const unsigned*)(Hb + (size_t)node * DIM))[lane];
    float2 bv = ((const float2*)bias)[lane];
    float ax = bf_lo(hv) * d2 + bv.x;
    float ay = bf_hi(hv) * d2 + bv.y;

    for (int e0 = beg; e0 < end; e0 += 64) {
        int cnt = end - e0;
        if (cnt > 64) cnt = 64;
        int2 rc = (lane < cnt) ? rec[e0 + lane] : make_int2(0, 0);
        int   sv = rc.x;
        float wv = __int_as_float(rc.y);
        int j = 0;
        for (; j + 3 < cnt; j += 4) {
            int   s0 = __shfl(sv, j, 64),     s1 = __shfl(sv, j + 1, 64);
            int   s2 = __shfl(sv, j + 2, 64), s3 = __shfl(sv, j + 3, 64);
            float w0 = __shfl(wv, j, 64),     w1 = __shfl(wv, j + 1, 64);
            float w2 = __shfl(wv, j + 2, 64), w3 = __shfl(wv, j + 3, 64);
            unsigned u0 = ((const unsigned*)(Hb + (size_t)s0 * DIM))[lane];
            unsigned u1 = ((const unsigned*)(Hb + (size_t)s1 * DIM))[lane];
            unsigned u2 = ((const unsigned*)(Hb + (size_t)s2 * DIM))[lane];
            unsigned u3 = ((const unsigned*)(Hb + (size_t)s3 * DIM))[lane];
            ax += bf_lo(u0) * w0 + bf_lo(u1) * w1 + bf_lo(u2) * w2 + bf_lo(u3) * w3;
            ay += bf_hi(u0) * w0 + bf_hi(u1) * w1 + bf_hi(u2) * w2 + bf_hi(u3) * w3;
        }
        for (; j < cnt; ++j) {
            int   s0 = __shfl(sv, j, 64);
            float w0 = __shfl(wv, j, 64);
            unsigned u0 = ((const unsigned*)(Hb + (size_t)s0 * DIM))[lane];
            ax += bf_lo(u0) * w0;
            ay += bf_hi(u0) * w0;
        }
    }

    // LayerNorm across 128 dims (wave-wide)
    float s1 = ax + ay;
    float s2 = ax * ax + ay * ay;
#pragma unroll
    for (int m = 1; m < 64; m <<= 1) {
        s1 += __shfl_xor(s1, m, 64);
        s2 += __shfl_xor(s2, m, 64);
    }
    float mean = s1 * (1.0f / 128.0f);
    float var  = s2 * (1.0f / 128.0f) - mean * mean;
    float r    = rsqrtf(var + 1e-5f);
    float2 gg = ((const float2*)g)[lane];
    float2 bb = ((const float2*)be)[lane];
    float a0 = (ax - mean) * r * gg.x + bb.x;
    float a1 = (ay - mean) * r * gg.y + bb.y;
    a0 = a0 > 0.0f ? a0 : expm1f(a0);
    a1 = a1 > 0.0f ? a1 : expm1f(a1);
    if (xin) {
        float2 xi = ((const float2*)(xin + (size_t)node * DIM))[lane];
        a0 += xi.x;
        a1 += xi.y;
    }
    ((float2*)(out + (size_t)node * DIM))[lane] = make_float2(a0, a1);
}

// ---------------------------------------------------------------- classifier: out = x @ Wc + bc
__global__ __launch_bounds__(256) void classifier(const float* __restrict__ X,
                                                  const float* __restrict__ Wc,
                                                  const float* __restrict__ bc,
                                                  float* __restrict__ out) {
    __shared__ float wc[DIM * NCLS];
    __shared__ float xs[64 * DIM];
    __shared__ float bcs[NCLS];
    const int tid  = threadIdx.x;
    const int row0 = blockIdx.x * 64;

#pragma unroll
    for (int i = 0; i < 20; ++i) wc[tid + i * 256] = Wc[tid + i * 256];
    if (tid < NCLS) bcs[tid] = bc[tid];

#pragma unroll
    for (int i = 0; i < 8; ++i) {
        int idx = tid + i * 256;
        int r   = idx >> 5;
        int c4  = idx & 31;
        int row = row0 + r;
        float4 v = (row < N_NODES)
                       ? ((const float4*)(X + (size_t)row * DIM))[c4]
                       : make_float4(0.f, 0.f, 0.f, 0.f);
        ((float4*)(xs + r * DIM))[c4] = v;
    }
    __syncthreads();

#pragma unroll
    for (int j = 0; j < 10; ++j) {
        int idx = tid + j * 256;
        int r   = idx / NCLS;
        int c   = idx % NCLS;
        int row = row0 + r;
        if (row < N_NODES) {
            float acc = bcs[c];
#pragma unroll 8
            for (int k = 0; k < DIM; ++k) acc += xs[r * DIM + k] * wc[k * NCLS + c];
            out[(size_t)row * NCLS + c] = acc;
        }
    }
}

// ---------------------------------------------------------------- launch
extern "C" void kernel_launch(void* const* d_in, const int* in_sizes, int n_in,
                              void* d_out, int out_size, void* d_ws, size_t ws_size,
                              hipStream_t stream) {
    const float* x  = (const float*)d_in[0];
    const int*   ei = (const int*)d_in[1];
    const float* W[3]  = {(const float*)d_in[2], (const float*)d_in[6], (const float*)d_in[10]};
    const float* b[3]  = {(const float*)d_in[3], (const float*)d_in[7], (const float*)d_in[11]};
    const float* g[3]  = {(const float*)d_in[4], (const float*)d_in[8], (const float*)d_in[12]};
    const float* be[3] = {(const float*)d_in[5], (const float*)d_in[9], (const float*)d_in[13]};
    const float* Wc = (const float*)d_in[14];
    const float* bc = (const float*)d_in[15];
    float* out = (float*)d_out;

    char* ws = (char*)d_ws;
    const size_t NP = 400128;  // padded N*4 bytes
    float* dinv   = (float*)(ws);
    int*   degi   = (int*)  (ws + NP);
    int*   rowptr = (int*)  (ws + 2 * NP);
    int*   ctr    = (int*)  (ws + 3 * NP);
    int*   bsums  = (int*)  (ws + 4 * NP);
    int2*  rec    = (int2*) (ws + 4 * NP + 512);
    unsigned short* Hb = (unsigned short*)(ws + 4 * NP + 512 + (size_t)N_EDGES * 8);
    float* A      = (float*)(ws + 4 * NP + 512 + (size_t)N_EDGES * 8 + (size_t)N_NODES * DIM * 2);
    float* C      = A + (size_t)N_NODES * DIM;

    // ---- CSR build ----
    hipMemsetAsync(degi, 0, N_NODES * sizeof(int), stream);
    deg_count<<<(N_EDGES + 255) / 256, 256, 0, stream>>>(ei, degi);
    finalize_dinv<<<(N_NODES + 255) / 256, 256, 0, stream>>>(degi, dinv);
    scan1<<<SCAN_BLOCKS, 256, 0, stream>>>(degi, rowptr, bsums);
    scan2<<<1, 128, 0, stream>>>(bsums);
    scan3<<<SCAN_BLOCKS * 4, 256, 0, stream>>>(rowptr, ctr, bsums);
    fill_csr<<<(N_EDGES + 255) / 256, 256, 0, stream>>>(ei, dinv, ctr, rec);

    const int gemm_grid = (N_NODES + 127) / 128;  // 782
    const int agg_grid  = N_NODES / 4;            // 25000

    // layer 0: x_in = x (no residual), h = Hb, out = C
    gemm128<<<gemm_grid, 256, 0, stream>>>(x, W[0], Hb);
    agg_ln<<<agg_grid, 256, 0, stream>>>(Hb, nullptr, dinv, b[0], g[0], be[0], rowptr, rec, C);

    // layer 1: x_in = C, h = Hb, out = A
    gemm128<<<gemm_grid, 256, 0, stream>>>(C, W[1], Hb);
    agg_ln<<<agg_grid, 256, 0, stream>>>(Hb, C, dinv, b[1], g[1], be[1], rowptr, rec, A);

    // layer 2: x_in = A, h = Hb, out = C
    gemm128<<<gemm_grid, 256, 0, stream>>>(A, W[2], Hb);
    agg_ln<<<agg_grid, 256, 0, stream>>>(Hb, A, dinv, b[2], g[2], be[2], rowptr, rec, C);

    classifier<<<(N_NODES + 63) / 64, 256, 0, stream>>>(C, Wc, bc, out);
}

// Round 4
// 764.850 us; speedup vs baseline: 5.9043x; 1.0094x over previous
//
#include <hip/hip_runtime.h>
#include <math.h>

#define N_NODES 100000
#define N_EDGES 1600000
#define DIM     128
#define NCLS    40
#define SCAN_BLOCKS 98   // ceil(100000/1024)

// bf16 helpers (manual RNE; bf16->f32 is a shift)
__device__ inline unsigned short bf16r(float f) {
    unsigned u = __float_as_uint(f);
    unsigned r = (u + 0x7fffu + ((u >> 16) & 1u)) >> 16;
    return (unsigned short)r;
}
__device__ inline unsigned pack_bf2(float lo, float hi) {
    return (unsigned)bf16r(lo) | ((unsigned)bf16r(hi) << 16);
}
__device__ inline float bf_lo(unsigned v) { return __uint_as_float(v << 16); }
__device__ inline float bf_hi(unsigned v) { return __uint_as_float(v & 0xffff0000u); }

// ---------------------------------------------------------------- degree (int)
__global__ __launch_bounds__(256) void deg_count(const int* __restrict__ ei,
                                                 int* __restrict__ degi) {
    int e = blockIdx.x * 256 + threadIdx.x;
    if (e < N_EDGES) atomicAdd(&degi[ei[N_EDGES + e]], 1);
}

__global__ __launch_bounds__(256) void finalize_dinv(const int* __restrict__ degi,
                                                     float* __restrict__ dinv) {
    int n = blockIdx.x * 256 + threadIdx.x;
    if (n < N_NODES) dinv[n] = rsqrtf((float)degi[n] + 1.0f);
}

// ---------------------------------------------------------------- scan (exclusive) over degi -> rowptr
__global__ __launch_bounds__(256) void scan1(const int* __restrict__ degi,
                                             int* __restrict__ rowptr,
                                             int* __restrict__ bsums) {
    __shared__ int sums[256];
    int t    = threadIdx.x;
    int base = blockIdx.x * 1024 + t * 4;
    int v[4], s = 0;
#pragma unroll
    for (int i = 0; i < 4; ++i) {
        int idx = base + i;
        v[i] = (idx < N_NODES) ? degi[idx] : 0;
        s += v[i];
    }
    sums[t] = s;
    __syncthreads();
    for (int off = 1; off < 256; off <<= 1) {
        int x = (t >= off) ? sums[t - off] : 0;
        __syncthreads();
        sums[t] += x;
        __syncthreads();
    }
    int run = (t == 0) ? 0 : sums[t - 1];
#pragma unroll
    for (int i = 0; i < 4; ++i) {
        int idx = base + i;
        if (idx < N_NODES) rowptr[idx] = run;
        run += v[i];
    }
    if (t == 255) bsums[blockIdx.x] = sums[255];
}

__global__ __launch_bounds__(128) void scan2(int* __restrict__ bsums) {
    __shared__ int s[128];
    int t = threadIdx.x;
    s[t] = (t < SCAN_BLOCKS) ? bsums[t] : 0;
    __syncthreads();
    for (int off = 1; off < 128; off <<= 1) {
        int x = (t >= off) ? s[t - off] : 0;
        __syncthreads();
        s[t] += x;
        __syncthreads();
    }
    if (t < SCAN_BLOCKS) bsums[t] = (t == 0) ? 0 : s[t - 1];
}

__global__ __launch_bounds__(256) void scan3(int* __restrict__ rowptr,
                                             int* __restrict__ ctr,
                                             const int* __restrict__ bsums) {
    int idx = blockIdx.x * 256 + threadIdx.x;
    if (idx < N_NODES) {
        int v = rowptr[idx] + bsums[idx >> 10];
        rowptr[idx] = v;
        ctr[idx]    = v;
    }
    if (idx == 0) rowptr[N_NODES] = N_EDGES;
}

// ---------------------------------------------------------------- fill CSR (by dst), interleaved (src, weight)
__global__ __launch_bounds__(256) void fill_csr(const int* __restrict__ ei,
                                                const float* __restrict__ dinv,
                                                int* __restrict__ ctr,
                                                int2* __restrict__ rec) {
    int e = blockIdx.x * 256 + threadIdx.x;
    if (e < N_EDGES) {
        int s = ei[e];
        int d = ei[N_EDGES + e];
        int pos = atomicAdd(&ctr[d], 1);
        rec[pos] = make_int2(s, __float_as_int(dinv[s] * dinv[d]));
    }
}

// ---------------------------------------------------------------- GEMM h = X @ W  (X: N x 128, W: 128 x 128) -> bf16
__global__ __launch_bounds__(256) void gemm128(const float* __restrict__ X,
                                               const float* __restrict__ W,
                                               unsigned short* __restrict__ H) {
    __shared__ float wlds[128 * 128];    // row-major [k][c]
    __shared__ float xt[128 * 132];      // transposed [k][r], stride 132
    const int tid  = threadIdx.x;
    const int row0 = blockIdx.x * 128;

    const float4* W4  = (const float4*)W;
    float4*       wl4 = (float4*)wlds;
#pragma unroll
    for (int i = 0; i < 16; ++i) wl4[tid + i * 256] = W4[tid + i * 256];

#pragma unroll
    for (int i = 0; i < 16; ++i) {
        int idx = tid + i * 256;             // 0..4095 float4s
        int c4l = idx & 3;
        int r   = (idx >> 2) & 127;
        int c4h = idx >> 9;                  // 0..7
        int c4  = c4h * 4 + c4l;
        int row = row0 + r;
        if (row >= N_NODES) row = N_NODES - 1;   // clamp (result unused)
        float4 v = ((const float4*)(X + (size_t)row * DIM))[c4];
        int c = c4 * 4;
        xt[(c + 0) * 132 + r] = v.x;
        xt[(c + 1) * 132 + r] = v.y;
        xt[(c + 2) * 132 + r] = v.z;
        xt[(c + 3) * 132 + r] = v.w;
    }
    __syncthreads();

    const int tr = tid >> 4;   // 0..15 -> rows tr*8..tr*8+7
    const int tc = tid & 15;   // 0..15 -> cols tc*8..tc*8+7
    const float* ap = xt + tr * 8;
    const float* bp = wlds + tc * 8;
    float acc[8][8] = {};
#pragma unroll 4
    for (int k = 0; k < 128; ++k) {
        float4 a0 = *(const float4*)(ap + k * 132);
        float4 a1 = *(const float4*)(ap + k * 132 + 4);
        float4 b0 = *(const float4*)(bp + k * 128);
        float4 b1 = *(const float4*)(bp + k * 128 + 4);
        float av[8] = {a0.x, a0.y, a0.z, a0.w, a1.x, a1.y, a1.z, a1.w};
        float bv[8] = {b0.x, b0.y, b0.z, b0.w, b1.x, b1.y, b1.z, b1.w};
#pragma unroll
        for (int i = 0; i < 8; ++i)
#pragma unroll
            for (int j = 0; j < 8; ++j) acc[i][j] += av[i] * bv[j];
    }

#pragma unroll
    for (int i = 0; i < 8; ++i) {
        int row = row0 + tr * 8 + i;
        if (row < N_NODES) {
            int4 o = make_int4((int)pack_bf2(acc[i][0], acc[i][1]),
                               (int)pack_bf2(acc[i][2], acc[i][3]),
                               (int)pack_bf2(acc[i][4], acc[i][5]),
                               (int)pack_bf2(acc[i][6], acc[i][7]));
            *(int4*)(H + (size_t)row * DIM + tc * 8) = o;
        }
    }
}

// ---------------------------------------------------------------- fused gather-aggregate + LN + ELU (+ residual)
__global__ __launch_bounds__(256) void agg_ln(const unsigned short* __restrict__ Hb,
                                              const float* __restrict__ xin,
                                              const float* __restrict__ dinv,
                                              const float* __restrict__ bias,
                                              const float* __restrict__ g,
                                              const float* __restrict__ be,
                                              const int* __restrict__ rowptr,
                                              const int2* __restrict__ rec,
                                              float* __restrict__ out) {
    int node = blockIdx.x * 4 + (threadIdx.x >> 6);
    int lane = threadIdx.x & 63;
    int beg = rowptr[node];
    int end = rowptr[node + 1];

    float dv = dinv[node];
    float d2 = dv * dv;
    unsigned hv = ((const unsigned*)(Hb + (size_t)node * DIM))[lane];
    float2 bv = ((const float2*)bias)[lane];
    float ax = bf_lo(hv) * d2 + bv.x;
    float ay = bf_hi(hv) * d2 + bv.y;

    for (int e0 = beg; e0 < end; e0 += 64) {
        int cnt = end - e0;
        if (cnt > 64) cnt = 64;
        int2 rc = (lane < cnt) ? rec[e0 + lane] : make_int2(0, 0);
        int   sv = rc.x;
        float wv = __int_as_float(rc.y);
        int j = 0;
        for (; j + 3 < cnt; j += 4) {
            int   s0 = __shfl(sv, j, 64),     s1 = __shfl(sv, j + 1, 64);
            int   s2 = __shfl(sv, j + 2, 64), s3 = __shfl(sv, j + 3, 64);
            float w0 = __shfl(wv, j, 64),     w1 = __shfl(wv, j + 1, 64);
            float w2 = __shfl(wv, j + 2, 64), w3 = __shfl(wv, j + 3, 64);
            unsigned u0 = ((const unsigned*)(Hb + (size_t)s0 * DIM))[lane];
            unsigned u1 = ((const unsigned*)(Hb + (size_t)s1 * DIM))[lane];
            unsigned u2 = ((const unsigned*)(Hb + (size_t)s2 * DIM))[lane];
            unsigned u3 = ((const unsigned*)(Hb + (size_t)s3 * DIM))[lane];
            ax += bf_lo(u0) * w0 + bf_lo(u1) * w1 + bf_lo(u2) * w2 + bf_lo(u3) * w3;
            ay += bf_hi(u0) * w0 + bf_hi(u1) * w1 + bf_hi(u2) * w2 + bf_hi(u3) * w3;
        }
        for (; j < cnt; ++j) {
            int   s0 = __shfl(sv, j, 64);
            float w0 = __shfl(wv, j, 64);
            unsigned u0 = ((const unsigned*)(Hb + (size_t)s0 * DIM))[lane];
            ax += bf_lo(u0) * w0;
            ay += bf_hi(u0) * w0;
        }
    }

    float s1 = ax + ay;
    float s2 = ax * ax + ay * ay;
#pragma unroll
    for (int m = 1; m < 64; m <<= 1) {
        s1 += __shfl_xor(s1, m, 64);
        s2 += __shfl_xor(s2, m, 64);
    }
    float mean = s1 * (1.0f / 128.0f);
    float var  = s2 * (1.0f / 128.0f) - mean * mean;
    float r    = rsqrtf(var + 1e-5f);
    float2 gg = ((const float2*)g)[lane];
    float2 bb = ((const float2*)be)[lane];
    float a0 = (ax - mean) * r * gg.x + bb.x;
    float a1 = (ay - mean) * r * gg.y + bb.y;
    a0 = a0 > 0.0f ? a0 : expm1f(a0);
    a1 = a1 > 0.0f ? a1 : expm1f(a1);
    if (xin) {
        float2 xi = ((const float2*)(xin + (size_t)node * DIM))[lane];
        a0 += xi.x;
        a1 += xi.y;
    }
    ((float2*)(out + (size_t)node * DIM))[lane] = make_float2(a0, a1);
}

// ---------------------------------------------------------------- classifier: out = x @ Wc + bc   (Wc: 128 x 40)
// 128 rows/block, 256 threads: thread (rp=tid>>2, cg=tid&3) computes rows
// {rp, rp+64} x cols {cg*10..cg*10+9}. X staged stride-132 (2-way bank = free),
// Wc staged transposed stride-132 (cg addresses hit distinct bank quartets).
__global__ __launch_bounds__(256) void classifier(const float* __restrict__ X,
                                                  const float* __restrict__ Wc,
                                                  const float* __restrict__ bc,
                                                  float* __restrict__ out) {
    __shared__ float xs[128 * 132];      // 67.6 KB
    __shared__ float wcT[NCLS * 132];    // 21.1 KB, [c][k]
    __shared__ float bcs[NCLS];
    const int tid  = threadIdx.x;
    const int row0 = blockIdx.x * 128;

    // stage Wc^T
    for (int idx = tid; idx < DIM * NCLS; idx += 256) {
        int k = idx / NCLS;
        int c = idx - k * NCLS;
        wcT[c * 132 + k] = Wc[idx];
    }
    if (tid < NCLS) bcs[tid] = bc[tid];

    // stage X rows (float4, coalesced)
#pragma unroll
    for (int i = 0; i < 16; ++i) {
        int idx = tid + i * 256;         // 0..4095 float4s
        int r   = idx >> 5;
        int c4  = idx & 31;
        int row = row0 + r;
        float4 v = (row < N_NODES)
                       ? ((const float4*)(X + (size_t)row * DIM))[c4]
                       : make_float4(0.f, 0.f, 0.f, 0.f);
        *(float4*)(xs + r * 132 + c4 * 4) = v;
    }
    __syncthreads();

    const int cg = tid & 3;              // col group: cols cg*10..cg*10+9
    const int rp = tid >> 2;             // 0..63
    const float* xa = xs + rp * 132;
    const float* xb = xs + (rp + 64) * 132;
    const float* wp = wcT + (cg * 10) * 132;

    float acc0[10] = {}, acc1[10] = {};
#pragma unroll 8
    for (int k = 0; k < DIM; k += 4) {
        float4 a0 = *(const float4*)(xa + k);
        float4 a1 = *(const float4*)(xb + k);
#pragma unroll
        for (int c = 0; c < 10; ++c) {
            float4 w = *(const float4*)(wp + c * 132 + k);
            acc0[c] += a0.x * w.x + a0.y * w.y + a0.z * w.z + a0.w * w.w;
            acc1[c] += a1.x * w.x + a1.y * w.y + a1.z * w.z + a1.w * w.w;
        }
    }

    int ra = row0 + rp;
    int rb = row0 + rp + 64;
    if (ra < N_NODES) {
#pragma unroll
        for (int c = 0; c < 10; ++c)
            out[(size_t)ra * NCLS + cg * 10 + c] = acc0[c] + bcs[cg * 10 + c];
    }
    if (rb < N_NODES) {
#pragma unroll
        for (int c = 0; c < 10; ++c)
            out[(size_t)rb * NCLS + cg * 10 + c] = acc1[c] + bcs[cg * 10 + c];
    }
}

// ---------------------------------------------------------------- launch
extern "C" void kernel_launch(void* const* d_in, const int* in_sizes, int n_in,
                              void* d_out, int out_size, void* d_ws, size_t ws_size,
                              hipStream_t stream) {
    const float* x  = (const float*)d_in[0];
    const int*   ei = (const int*)d_in[1];
    const float* W[3]  = {(const float*)d_in[2], (const float*)d_in[6], (const float*)d_in[10]};
    const float* b[3]  = {(const float*)d_in[3], (const float*)d_in[7], (const float*)d_in[11]};
    const float* g[3]  = {(const float*)d_in[4], (const float*)d_in[8], (const float*)d_in[12]};
    const float* be[3] = {(const float*)d_in[5], (const float*)d_in[9], (const float*)d_in[13]};
    const float* Wc = (const float*)d_in[14];
    const float* bc = (const float*)d_in[15];
    float* out = (float*)d_out;

    char* ws = (char*)d_ws;
    const size_t NP = 400128;  // padded N*4 bytes
    float* dinv   = (float*)(ws);
    int*   degi   = (int*)  (ws + NP);
    int*   rowptr = (int*)  (ws + 2 * NP);
    int*   ctr    = (int*)  (ws + 3 * NP);
    int*   bsums  = (int*)  (ws + 4 * NP);
    int2*  rec    = (int2*) (ws + 4 * NP + 512);
    unsigned short* Hb = (unsigned short*)(ws + 4 * NP + 512 + (size_t)N_EDGES * 8);
    float* A      = (float*)(ws + 4 * NP + 512 + (size_t)N_EDGES * 8 + (size_t)N_NODES * DIM * 2);
    float* C      = A + (size_t)N_NODES * DIM;

    // ---- CSR build ----
    hipMemsetAsync(degi, 0, N_NODES * sizeof(int), stream);
    deg_count<<<(N_EDGES + 255) / 256, 256, 0, stream>>>(ei, degi);
    finalize_dinv<<<(N_NODES + 255) / 256, 256, 0, stream>>>(degi, dinv);
    scan1<<<SCAN_BLOCKS, 256, 0, stream>>>(degi, rowptr, bsums);
    scan2<<<1, 128, 0, stream>>>(bsums);
    scan3<<<SCAN_BLOCKS * 4, 256, 0, stream>>>(rowptr, ctr, bsums);
    fill_csr<<<(N_EDGES + 255) / 256, 256, 0, stream>>>(ei, dinv, ctr, rec);

    const int gemm_grid = (N_NODES + 127) / 128;  // 782
    const int agg_grid  = N_NODES / 4;            // 25000

    // layer 0
    gemm128<<<gemm_grid, 256, 0, stream>>>(x, W[0], Hb);
    agg_ln<<<agg_grid, 256, 0, stream>>>(Hb, nullptr, dinv, b[0], g[0], be[0], rowptr, rec, C);

    // layer 1
    gemm128<<<gemm_grid, 256, 0, stream>>>(C, W[1], Hb);
    agg_ln<<<agg_grid, 256, 0, stream>>>(Hb, C, dinv, b[1], g[1], be[1], rowptr, rec, A);

    // layer 2
    gemm128<<<gemm_grid, 256, 0, stream>>>(A, W[2], Hb);
    agg_ln<<<agg_grid, 256, 0, stream>>>(Hb, A, dinv, b[2], g[2], be[2], rowptr, rec, C);

    classifier<<<(N_NODES + 127) / 128, 256, 0, stream>>>(C, Wc, bc, out);
}

// Round 5
// 625.576 us; speedup vs baseline: 7.2188x; 1.2226x over previous
//
#include <hip/hip_runtime.h>
#include <math.h>

#define N_NODES 100000
#define N_EDGES 1600000
#define DIM     128
#define NCLS    40
#define SCAN_BLOCKS 98   // ceil(100000/1024)

typedef __attribute__((ext_vector_type(8))) short bf16x8;
typedef __attribute__((ext_vector_type(4))) float f32x4;

// bf16 helpers (manual RNE; bf16->f32 is a shift)
__device__ inline unsigned short bf16r(float f) {
    unsigned u = __float_as_uint(f);
    unsigned r = (u + 0x7fffu + ((u >> 16) & 1u)) >> 16;
    return (unsigned short)r;
}
__device__ inline unsigned pack_bf2(float lo, float hi) {
    return (unsigned)bf16r(lo) | ((unsigned)bf16r(hi) << 16);
}
__device__ inline float bf_lo(unsigned v) { return __uint_as_float(v << 16); }
__device__ inline float bf_hi(unsigned v) { return __uint_as_float(v & 0xffff0000u); }

// ---------------------------------------------------------------- degree (int)
__global__ __launch_bounds__(256) void deg_count(const int* __restrict__ ei,
                                                 int* __restrict__ degi) {
    int e = blockIdx.x * 256 + threadIdx.x;
    if (e < N_EDGES) atomicAdd(&degi[ei[N_EDGES + e]], 1);
}

__global__ __launch_bounds__(256) void finalize_dinv(const int* __restrict__ degi,
                                                     float* __restrict__ dinv) {
    int n = blockIdx.x * 256 + threadIdx.x;
    if (n < N_NODES) dinv[n] = rsqrtf((float)degi[n] + 1.0f);
}

// ---------------------------------------------------------------- scan (exclusive) over degi -> rowptr
__global__ __launch_bounds__(256) void scan1(const int* __restrict__ degi,
                                             int* __restrict__ rowptr,
                                             int* __restrict__ bsums) {
    __shared__ int sums[256];
    int t    = threadIdx.x;
    int base = blockIdx.x * 1024 + t * 4;
    int v[4], s = 0;
#pragma unroll
    for (int i = 0; i < 4; ++i) {
        int idx = base + i;
        v[i] = (idx < N_NODES) ? degi[idx] : 0;
        s += v[i];
    }
    sums[t] = s;
    __syncthreads();
    for (int off = 1; off < 256; off <<= 1) {
        int x = (t >= off) ? sums[t - off] : 0;
        __syncthreads();
        sums[t] += x;
        __syncthreads();
    }
    int run = (t == 0) ? 0 : sums[t - 1];
#pragma unroll
    for (int i = 0; i < 4; ++i) {
        int idx = base + i;
        if (idx < N_NODES) rowptr[idx] = run;
        run += v[i];
    }
    if (t == 255) bsums[blockIdx.x] = sums[255];
}

__global__ __launch_bounds__(128) void scan2(int* __restrict__ bsums) {
    __shared__ int s[128];
    int t = threadIdx.x;
    s[t] = (t < SCAN_BLOCKS) ? bsums[t] : 0;
    __syncthreads();
    for (int off = 1; off < 128; off <<= 1) {
        int x = (t >= off) ? s[t - off] : 0;
        __syncthreads();
        s[t] += x;
        __syncthreads();
    }
    if (t < SCAN_BLOCKS) bsums[t] = (t == 0) ? 0 : s[t - 1];
}

__global__ __launch_bounds__(256) void scan3(int* __restrict__ rowptr,
                                             int* __restrict__ ctr,
                                             const int* __restrict__ bsums) {
    int idx = blockIdx.x * 256 + threadIdx.x;
    if (idx < N_NODES) {
        int v = rowptr[idx] + bsums[idx >> 10];
        rowptr[idx] = v;
        ctr[idx]    = v;
    }
    if (idx == 0) rowptr[N_NODES] = N_EDGES;
}

// ---------------------------------------------------------------- fill CSR (by dst), interleaved (src, weight)
__global__ __launch_bounds__(256) void fill_csr(const int* __restrict__ ei,
                                                const float* __restrict__ dinv,
                                                int* __restrict__ ctr,
                                                int2* __restrict__ rec) {
    int e = blockIdx.x * 256 + threadIdx.x;
    if (e < N_EDGES) {
        int s = ei[e];
        int d = ei[N_EDGES + e];
        int pos = atomicAdd(&ctr[d], 1);
        rec[pos] = make_int2(s, __float_as_int(dinv[s] * dinv[d]));
    }
}

// ---------------------------------------------------------------- W pre-swizzle into MFMA B-fragment order (bf16)
// Frag f = n*4 + s (ntile, kstep). Wsw[f*512 + l*8 + j] = W[k][c],
// k = s*32 + (l>>4)*8 + j,  c = (l&15)*8 + n   (tile n covers cols == n mod 8)
__global__ __launch_bounds__(256) void wswz(const float* __restrict__ W,
                                            unsigned short* __restrict__ Wsw) {
    int o = blockIdx.x * 256 + threadIdx.x;      // 0..16383
    int f = o >> 9;
    int l = (o >> 3) & 63;
    int j = o & 7;
    int n = f >> 2;
    int s = f & 3;
    int k = s * 32 + (l >> 4) * 8 + j;
    int c = (l & 15) * 8 + n;
    Wsw[o] = bf16r(W[k * DIM + c]);
}

// ---------------------------------------------------------------- MFMA GEMM: H(bf16) = X(fp32) @ W  (K=128, no LDS)
// Block = 4 waves, 64 rows. Each wave: 16 rows x 128 cols, W frags in registers.
__global__ __launch_bounds__(256, 2) void gemm_mfma(const float* __restrict__ X,
                                                    const unsigned short* __restrict__ Wsw,
                                                    unsigned short* __restrict__ H) {
    const int lane  = threadIdx.x & 63;
    const int wave  = threadIdx.x >> 6;
    const int row0w = blockIdx.x * 64 + wave * 16;
    const int m = lane & 15;
    const int q = lane >> 4;

    // all 32 B-frags (32 KB, L2-hot, coalesced 1KB/inst)
    bf16x8 wf[32];
#pragma unroll
    for (int f = 0; f < 32; ++f)
        wf[f] = *(const bf16x8*)(Wsw + (f << 9) + lane * 8);

    // A: 16 rows x 128 k, lane holds row m, k-chunk q*8..q*8+8 per kstep
    int r = row0w + m;
    if (r >= N_NODES) r = N_NODES - 1;           // clamp; stores guarded
    const float* xp = X + (size_t)r * DIM + q * 8;
    float4 xa[8];
#pragma unroll
    for (int s = 0; s < 4; ++s) {
        xa[2 * s]     = *(const float4*)(xp + s * 32);
        xa[2 * s + 1] = *(const float4*)(xp + s * 32 + 4);
    }
    bf16x8 af[4];
#pragma unroll
    for (int s = 0; s < 4; ++s) {
        union { bf16x8 v; unsigned u[4]; } t;
        t.u[0] = pack_bf2(xa[2 * s].x, xa[2 * s].y);
        t.u[1] = pack_bf2(xa[2 * s].z, xa[2 * s].w);
        t.u[2] = pack_bf2(xa[2 * s + 1].x, xa[2 * s + 1].y);
        t.u[3] = pack_bf2(xa[2 * s + 1].z, xa[2 * s + 1].w);
        af[s] = t.v;
    }

    f32x4 acc[8];
    f32x4 z = {0.f, 0.f, 0.f, 0.f};
#pragma unroll
    for (int n = 0; n < 8; ++n) acc[n] = z;

#pragma unroll
    for (int s = 0; s < 4; ++s)
#pragma unroll
        for (int n = 0; n < 8; ++n)
            acc[n] = __builtin_amdgcn_mfma_f32_16x16x32_bf16(af[s], wf[n * 4 + s], acc[n], 0, 0, 0);

    // epilogue: lane (m,q) holds rows q*4+j, cols m*8..m*8+7 (n-contiguous by construction)
#pragma unroll
    for (int j = 0; j < 4; ++j) {
        int row = row0w + q * 4 + j;
        if (row < N_NODES) {
            int4 o = make_int4((int)pack_bf2(acc[0][j], acc[1][j]),
                               (int)pack_bf2(acc[2][j], acc[3][j]),
                               (int)pack_bf2(acc[4][j], acc[5][j]),
                               (int)pack_bf2(acc[6][j], acc[7][j]));
            *(int4*)(H + (size_t)row * DIM + m * 8) = o;
        }
    }
}

// ---------------------------------------------------------------- fused gather-aggregate + LN + ELU (+ residual)
__global__ __launch_bounds__(256) void agg_ln(const unsigned short* __restrict__ Hb,
                                              const float* __restrict__ xin,
                                              const float* __restrict__ dinv,
                                              const float* __restrict__ bias,
                                              const float* __restrict__ g,
                                              const float* __restrict__ be,
                                              const int* __restrict__ rowptr,
                                              const int2* __restrict__ rec,
                                              float* __restrict__ out) {
    int node = blockIdx.x * 4 + (threadIdx.x >> 6);
    int lane = threadIdx.x & 63;
    int beg = rowptr[node];
    int end = rowptr[node + 1];

    float dv = dinv[node];
    float d2 = dv * dv;
    unsigned hv = ((const unsigned*)(Hb + (size_t)node * DIM))[lane];
    float2 bv = ((const float2*)bias)[lane];
    float ax = bf_lo(hv) * d2 + bv.x;
    float ay = bf_hi(hv) * d2 + bv.y;

    for (int e0 = beg; e0 < end; e0 += 64) {
        int cnt = end - e0;
        if (cnt > 64) cnt = 64;
        int2 rc = (lane < cnt) ? rec[e0 + lane] : make_int2(0, 0);
        int   sv = rc.x;
        float wv = __int_as_float(rc.y);
        int j = 0;
        for (; j + 3 < cnt; j += 4) {
            int   s0 = __shfl(sv, j, 64),     s1 = __shfl(sv, j + 1, 64);
            int   s2 = __shfl(sv, j + 2, 64), s3 = __shfl(sv, j + 3, 64);
            float w0 = __shfl(wv, j, 64),     w1 = __shfl(wv, j + 1, 64);
            float w2 = __shfl(wv, j + 2, 64), w3 = __shfl(wv, j + 3, 64);
            unsigned u0 = ((const unsigned*)(Hb + (size_t)s0 * DIM))[lane];
            unsigned u1 = ((const unsigned*)(Hb + (size_t)s1 * DIM))[lane];
            unsigned u2 = ((const unsigned*)(Hb + (size_t)s2 * DIM))[lane];
            unsigned u3 = ((const unsigned*)(Hb + (size_t)s3 * DIM))[lane];
            ax += bf_lo(u0) * w0 + bf_lo(u1) * w1 + bf_lo(u2) * w2 + bf_lo(u3) * w3;
            ay += bf_hi(u0) * w0 + bf_hi(u1) * w1 + bf_hi(u2) * w2 + bf_hi(u3) * w3;
        }
        for (; j < cnt; ++j) {
            int   s0 = __shfl(sv, j, 64);
            float w0 = __shfl(wv, j, 64);
            unsigned u0 = ((const unsigned*)(Hb + (size_t)s0 * DIM))[lane];
            ax += bf_lo(u0) * w0;
            ay += bf_hi(u0) * w0;
        }
    }

    float s1 = ax + ay;
    float s2 = ax * ax + ay * ay;
#pragma unroll
    for (int mm = 1; mm < 64; mm <<= 1) {
        s1 += __shfl_xor(s1, mm, 64);
        s2 += __shfl_xor(s2, mm, 64);
    }
    float mean = s1 * (1.0f / 128.0f);
    float var  = s2 * (1.0f / 128.0f) - mean * mean;
    float rr   = rsqrtf(var + 1e-5f);
    float2 gg = ((const float2*)g)[lane];
    float2 bb = ((const float2*)be)[lane];
    float a0 = (ax - mean) * rr * gg.x + bb.x;
    float a1 = (ay - mean) * rr * gg.y + bb.y;
    a0 = a0 > 0.0f ? a0 : expm1f(a0);
    a1 = a1 > 0.0f ? a1 : expm1f(a1);
    if (xin) {
        float2 xi = ((const float2*)(xin + (size_t)node * DIM))[lane];
        a0 += xi.x;
        a1 += xi.y;
    }
    ((float2*)(out + (size_t)node * DIM))[lane] = make_float2(a0, a1);
}

// ---------------------------------------------------------------- classifier: out = x @ Wc + bc   (Wc: 128 x 40)
__global__ __launch_bounds__(256) void classifier(const float* __restrict__ X,
                                                  const float* __restrict__ Wc,
                                                  const float* __restrict__ bc,
                                                  float* __restrict__ out) {
    __shared__ float xs[128 * 132];      // 67.6 KB
    __shared__ float wcT[NCLS * 132];    // 21.1 KB, [c][k]
    __shared__ float bcs[NCLS];
    const int tid  = threadIdx.x;
    const int row0 = blockIdx.x * 128;

    for (int idx = tid; idx < DIM * NCLS; idx += 256) {
        int k = idx / NCLS;
        int c = idx - k * NCLS;
        wcT[c * 132 + k] = Wc[idx];
    }
    if (tid < NCLS) bcs[tid] = bc[tid];

#pragma unroll
    for (int i = 0; i < 16; ++i) {
        int idx = tid + i * 256;
        int r   = idx >> 5;
        int c4  = idx & 31;
        int row = row0 + r;
        float4 v = (row < N_NODES)
                       ? ((const float4*)(X + (size_t)row * DIM))[c4]
                       : make_float4(0.f, 0.f, 0.f, 0.f);
        *(float4*)(xs + r * 132 + c4 * 4) = v;
    }
    __syncthreads();

    const int cg = tid & 3;
    const int rp = tid >> 2;
    const float* xa = xs + rp * 132;
    const float* xb = xs + (rp + 64) * 132;
    const float* wp = wcT + (cg * 10) * 132;

    float acc0[10] = {}, acc1[10] = {};
#pragma unroll 8
    for (int k = 0; k < DIM; k += 4) {
        float4 a0 = *(const float4*)(xa + k);
        float4 a1 = *(const float4*)(xb + k);
#pragma unroll
        for (int c = 0; c < 10; ++c) {
            float4 w = *(const float4*)(wp + c * 132 + k);
            acc0[c] += a0.x * w.x + a0.y * w.y + a0.z * w.z + a0.w * w.w;
            acc1[c] += a1.x * w.x + a1.y * w.y + a1.z * w.z + a1.w * w.w;
        }
    }

    int ra = row0 + rp;
    int rb = row0 + rp + 64;
    if (ra < N_NODES) {
#pragma unroll
        for (int c = 0; c < 10; ++c)
            out[(size_t)ra * NCLS + cg * 10 + c] = acc0[c] + bcs[cg * 10 + c];
    }
    if (rb < N_NODES) {
#pragma unroll
        for (int c = 0; c < 10; ++c)
            out[(size_t)rb * NCLS + cg * 10 + c] = acc1[c] + bcs[cg * 10 + c];
    }
}

// ---------------------------------------------------------------- launch
extern "C" void kernel_launch(void* const* d_in, const int* in_sizes, int n_in,
                              void* d_out, int out_size, void* d_ws, size_t ws_size,
                              hipStream_t stream) {
    const float* x  = (const float*)d_in[0];
    const int*   ei = (const int*)d_in[1];
    const float* W[3]  = {(const float*)d_in[2], (const float*)d_in[6], (const float*)d_in[10]};
    const float* b[3]  = {(const float*)d_in[3], (const float*)d_in[7], (const float*)d_in[11]};
    const float* g[3]  = {(const float*)d_in[4], (const float*)d_in[8], (const float*)d_in[12]};
    const float* be[3] = {(const float*)d_in[5], (const float*)d_in[9], (const float*)d_in[13]};
    const float* Wc = (const float*)d_in[14];
    const float* bc = (const float*)d_in[15];
    float* out = (float*)d_out;

    char* ws = (char*)d_ws;
    const size_t NP = 400128;  // padded N*4 bytes
    float* dinv   = (float*)(ws);
    int*   degi   = (int*)  (ws + NP);
    int*   rowptr = (int*)  (ws + 2 * NP);
    int*   ctr    = (int*)  (ws + 3 * NP);
    int*   bsums  = (int*)  (ws + 4 * NP);
    int2*  rec    = (int2*) (ws + 4 * NP + 512);
    unsigned short* Hb = (unsigned short*)(ws + 4 * NP + 512 + (size_t)N_EDGES * 8);
    float* A      = (float*)(ws + 4 * NP + 512 + (size_t)N_EDGES * 8 + (size_t)N_NODES * DIM * 2);
    float* C      = A + (size_t)N_NODES * DIM;
    unsigned short* Wsw0 = (unsigned short*)(C + (size_t)N_NODES * DIM);
    unsigned short* Wsw1 = Wsw0 + DIM * DIM;
    unsigned short* Wsw2 = Wsw1 + DIM * DIM;

    // ---- W pre-swizzle (bf16, MFMA B-frag order) ----
    wswz<<<64, 256, 0, stream>>>(W[0], Wsw0);
    wswz<<<64, 256, 0, stream>>>(W[1], Wsw1);
    wswz<<<64, 256, 0, stream>>>(W[2], Wsw2);

    // ---- CSR build ----
    hipMemsetAsync(degi, 0, N_NODES * sizeof(int), stream);
    deg_count<<<(N_EDGES + 255) / 256, 256, 0, stream>>>(ei, degi);
    finalize_dinv<<<(N_NODES + 255) / 256, 256, 0, stream>>>(degi, dinv);
    scan1<<<SCAN_BLOCKS, 256, 0, stream>>>(degi, rowptr, bsums);
    scan2<<<1, 128, 0, stream>>>(bsums);
    scan3<<<SCAN_BLOCKS * 4, 256, 0, stream>>>(rowptr, ctr, bsums);
    fill_csr<<<(N_EDGES + 255) / 256, 256, 0, stream>>>(ei, dinv, ctr, rec);

    const int gemm_grid = (N_NODES + 63) / 64;    // 1563
    const int agg_grid  = N_NODES / 4;            // 25000

    // layer 0
    gemm_mfma<<<gemm_grid, 256, 0, stream>>>(x, Wsw0, Hb);
    agg_ln<<<agg_grid, 256, 0, stream>>>(Hb, nullptr, dinv, b[0], g[0], be[0], rowptr, rec, C);

    // layer 1
    gemm_mfma<<<gemm_grid, 256, 0, stream>>>(C, Wsw1, Hb);
    agg_ln<<<agg_grid, 256, 0, stream>>>(Hb, C, dinv, b[1], g[1], be[1], rowptr, rec, A);

    // layer 2
    gemm_mfma<<<gemm_grid, 256, 0, stream>>>(A, Wsw2, Hb);
    agg_ln<<<agg_grid, 256, 0, stream>>>(Hb, A, dinv, b[2], g[2], be[2], rowptr, rec, C);

    classifier<<<(N_NODES + 127) / 128, 256, 0, stream>>>(C, Wc, bc, out);
}

// Round 6
// 563.196 us; speedup vs baseline: 8.0183x; 1.1108x over previous
//
#include <hip/hip_runtime.h>
#include <math.h>

#define N_NODES 100000
#define N_EDGES 1600000
#define DIM     128
#define NCLS    40
#define SCAN_BLOCKS 98   // ceil(100000/1024)

typedef __attribute__((ext_vector_type(8))) short bf16x8;
typedef __attribute__((ext_vector_type(4))) float f32x4;

// bf16 helpers (manual RNE; bf16->f32 is a shift)
__device__ inline unsigned short bf16r(float f) {
    unsigned u = __float_as_uint(f);
    unsigned r = (u + 0x7fffu + ((u >> 16) & 1u)) >> 16;
    return (unsigned short)r;
}
__device__ inline unsigned pack_bf2(float lo, float hi) {
    return (unsigned)bf16r(lo) | ((unsigned)bf16r(hi) << 16);
}
__device__ inline float bf_lo(unsigned v) { return __uint_as_float(v << 16); }
__device__ inline float bf_hi(unsigned v) { return __uint_as_float(v & 0xffff0000u); }

// ---------------------------------------------------------------- degree (int)
__global__ __launch_bounds__(256) void deg_count(const int* __restrict__ ei,
                                                 int* __restrict__ degi) {
    int e = blockIdx.x * 256 + threadIdx.x;
    if (e < N_EDGES) atomicAdd(&degi[ei[N_EDGES + e]], 1);
}

__global__ __launch_bounds__(256) void finalize_dinv(const int* __restrict__ degi,
                                                     float* __restrict__ dinv) {
    int n = blockIdx.x * 256 + threadIdx.x;
    if (n < N_NODES) dinv[n] = rsqrtf((float)degi[n] + 1.0f);
}

// ---------------------------------------------------------------- scan (exclusive) over degi -> rowptr
__global__ __launch_bounds__(256) void scan1(const int* __restrict__ degi,
                                             int* __restrict__ rowptr,
                                             int* __restrict__ bsums) {
    __shared__ int sums[256];
    int t    = threadIdx.x;
    int base = blockIdx.x * 1024 + t * 4;
    int v[4], s = 0;
#pragma unroll
    for (int i = 0; i < 4; ++i) {
        int idx = base + i;
        v[i] = (idx < N_NODES) ? degi[idx] : 0;
        s += v[i];
    }
    sums[t] = s;
    __syncthreads();
    for (int off = 1; off < 256; off <<= 1) {
        int x = (t >= off) ? sums[t - off] : 0;
        __syncthreads();
        sums[t] += x;
        __syncthreads();
    }
    int run = (t == 0) ? 0 : sums[t - 1];
#pragma unroll
    for (int i = 0; i < 4; ++i) {
        int idx = base + i;
        if (idx < N_NODES) rowptr[idx] = run;
        run += v[i];
    }
    if (t == 255) bsums[blockIdx.x] = sums[255];
}

__global__ __launch_bounds__(128) void scan2(int* __restrict__ bsums) {
    __shared__ int s[128];
    int t = threadIdx.x;
    s[t] = (t < SCAN_BLOCKS) ? bsums[t] : 0;
    __syncthreads();
    for (int off = 1; off < 128; off <<= 1) {
        int x = (t >= off) ? s[t - off] : 0;
        __syncthreads();
        s[t] += x;
        __syncthreads();
    }
    if (t < SCAN_BLOCKS) bsums[t] = (t == 0) ? 0 : s[t - 1];
}

__global__ __launch_bounds__(256) void scan3(int* __restrict__ rowptr,
                                             int* __restrict__ ctr,
                                             const int* __restrict__ bsums) {
    int idx = blockIdx.x * 256 + threadIdx.x;
    if (idx < N_NODES) {
        int v = rowptr[idx] + bsums[idx >> 10];
        rowptr[idx] = v;
        ctr[idx]    = v;
    }
    if (idx == 0) rowptr[N_NODES] = N_EDGES;
}

// ---------------------------------------------------------------- fill CSR (by dst), interleaved (src, weight)
__global__ __launch_bounds__(256) void fill_csr(const int* __restrict__ ei,
                                                const float* __restrict__ dinv,
                                                int* __restrict__ ctr,
                                                int2* __restrict__ rec) {
    int e = blockIdx.x * 256 + threadIdx.x;
    if (e < N_EDGES) {
        int s = ei[e];
        int d = ei[N_EDGES + e];
        int pos = atomicAdd(&ctr[d], 1);
        rec[pos] = make_int2(s, __float_as_int(dinv[s] * dinv[d]));
    }
}

// ---------------------------------------------------------------- W pre-swizzle into MFMA B-fragment order (bf16)
// Frag f = n*4 + s (ntile, kstep). Wsw[f*512 + l*8 + j] = W[k][c],
// k = s*32 + (l>>4)*8 + j,  c = (l&15)*8 + n
__global__ __launch_bounds__(256) void wswz(const float* __restrict__ W,
                                            unsigned short* __restrict__ Wsw) {
    int o = blockIdx.x * 256 + threadIdx.x;      // 0..16383
    int f = o >> 9;
    int l = (o >> 3) & 63;
    int j = o & 7;
    int n = f >> 2;
    int s = f & 3;
    int k = s * 32 + (l >> 4) * 8 + j;
    int c = (l & 15) * 8 + n;
    Wsw[o] = bf16r(W[k * DIM + c]);
}

// ---------------------------------------------------------------- Wc pre-swizzle (128x40 -> 3 n-tiles of 16 cols, c = 3m+n)
__global__ __launch_bounds__(256) void wcswz(const float* __restrict__ Wc,
                                             unsigned short* __restrict__ Wcsw) {
    int o = blockIdx.x * 256 + threadIdx.x;      // 0..6143 (12 frags x 512)
    if (o >= 12 * 512) return;
    int f = o >> 9;                              // 0..11
    int l = (o >> 3) & 63;
    int j = o & 7;
    int n = f >> 2;                              // 0..2
    int s = f & 3;
    int k = s * 32 + (l >> 4) * 8 + j;
    int c = (l & 15) * 3 + n;                    // 0..47
    Wcsw[o] = (c < NCLS) ? bf16r(Wc[k * NCLS + c]) : (unsigned short)0;
}

// ---------------------------------------------------------------- MFMA GEMM: H(bf16) = X(fp32) @ W  (K=128, no LDS)
__global__ __launch_bounds__(256, 2) void gemm_mfma(const float* __restrict__ X,
                                                    const unsigned short* __restrict__ Wsw,
                                                    unsigned short* __restrict__ H) {
    const int lane  = threadIdx.x & 63;
    const int wave  = threadIdx.x >> 6;
    const int row0w = blockIdx.x * 64 + wave * 16;
    const int m = lane & 15;
    const int q = lane >> 4;

    bf16x8 wf[32];
#pragma unroll
    for (int f = 0; f < 32; ++f)
        wf[f] = *(const bf16x8*)(Wsw + (f << 9) + lane * 8);

    int r = row0w + m;
    if (r >= N_NODES) r = N_NODES - 1;           // clamp; stores guarded
    const float* xp = X + (size_t)r * DIM + q * 8;
    float4 xa[8];
#pragma unroll
    for (int s = 0; s < 4; ++s) {
        xa[2 * s]     = *(const float4*)(xp + s * 32);
        xa[2 * s + 1] = *(const float4*)(xp + s * 32 + 4);
    }
    bf16x8 af[4];
#pragma unroll
    for (int s = 0; s < 4; ++s) {
        union { bf16x8 v; unsigned u[4]; } t;
        t.u[0] = pack_bf2(xa[2 * s].x, xa[2 * s].y);
        t.u[1] = pack_bf2(xa[2 * s].z, xa[2 * s].w);
        t.u[2] = pack_bf2(xa[2 * s + 1].x, xa[2 * s + 1].y);
        t.u[3] = pack_bf2(xa[2 * s + 1].z, xa[2 * s + 1].w);
        af[s] = t.v;
    }

    f32x4 acc[8];
    f32x4 z = {0.f, 0.f, 0.f, 0.f};
#pragma unroll
    for (int n = 0; n < 8; ++n) acc[n] = z;

#pragma unroll
    for (int s = 0; s < 4; ++s)
#pragma unroll
        for (int n = 0; n < 8; ++n)
            acc[n] = __builtin_amdgcn_mfma_f32_16x16x32_bf16(af[s], wf[n * 4 + s], acc[n], 0, 0, 0);

#pragma unroll
    for (int j = 0; j < 4; ++j) {
        int row = row0w + q * 4 + j;
        if (row < N_NODES) {
            int4 o = make_int4((int)pack_bf2(acc[0][j], acc[1][j]),
                               (int)pack_bf2(acc[2][j], acc[3][j]),
                               (int)pack_bf2(acc[4][j], acc[5][j]),
                               (int)pack_bf2(acc[6][j], acc[7][j]));
            *(int4*)(H + (size_t)row * DIM + m * 8) = o;
        }
    }
}

// ---------------------------------------------------------------- fused gather-aggregate + LN + ELU (+ residual)
__global__ __launch_bounds__(256) void agg_ln(const unsigned short* __restrict__ Hb,
                                              const float* __restrict__ xin,
                                              const float* __restrict__ dinv,
                                              const float* __restrict__ bias,
                                              const float* __restrict__ g,
                                              const float* __restrict__ be,
                                              const int* __restrict__ rowptr,
                                              const int2* __restrict__ rec,
                                              float* __restrict__ out) {
    int node = blockIdx.x * 4 + (threadIdx.x >> 6);
    int lane = threadIdx.x & 63;
    int beg = rowptr[node];
    int end = rowptr[node + 1];

    float dv = dinv[node];
    float d2 = dv * dv;
    unsigned hv = ((const unsigned*)(Hb + (size_t)node * DIM))[lane];
    float2 bv = ((const float2*)bias)[lane];
    float ax = bf_lo(hv) * d2 + bv.x;
    float ay = bf_hi(hv) * d2 + bv.y;

    for (int e0 = beg; e0 < end; e0 += 64) {
        int cnt = end - e0;
        if (cnt > 64) cnt = 64;
        int2 rc = (lane < cnt) ? rec[e0 + lane] : make_int2(0, 0);
        int   sv = rc.x;
        float wv = __int_as_float(rc.y);
        int j = 0;
        for (; j + 3 < cnt; j += 4) {
            int   s0 = __shfl(sv, j, 64),     s1 = __shfl(sv, j + 1, 64);
            int   s2 = __shfl(sv, j + 2, 64), s3 = __shfl(sv, j + 3, 64);
            float w0 = __shfl(wv, j, 64),     w1 = __shfl(wv, j + 1, 64);
            float w2 = __shfl(wv, j + 2, 64), w3 = __shfl(wv, j + 3, 64);
            unsigned u0 = ((const unsigned*)(Hb + (size_t)s0 * DIM))[lane];
            unsigned u1 = ((const unsigned*)(Hb + (size_t)s1 * DIM))[lane];
            unsigned u2 = ((const unsigned*)(Hb + (size_t)s2 * DIM))[lane];
            unsigned u3 = ((const unsigned*)(Hb + (size_t)s3 * DIM))[lane];
            ax += bf_lo(u0) * w0 + bf_lo(u1) * w1 + bf_lo(u2) * w2 + bf_lo(u3) * w3;
            ay += bf_hi(u0) * w0 + bf_hi(u1) * w1 + bf_hi(u2) * w2 + bf_hi(u3) * w3;
        }
        for (; j < cnt; ++j) {
            int   s0 = __shfl(sv, j, 64);
            float w0 = __shfl(wv, j, 64);
            unsigned u0 = ((const unsigned*)(Hb + (size_t)s0 * DIM))[lane];
            ax += bf_lo(u0) * w0;
            ay += bf_hi(u0) * w0;
        }
    }

    float s1 = ax + ay;
    float s2 = ax * ax + ay * ay;
#pragma unroll
    for (int mm = 1; mm < 64; mm <<= 1) {
        s1 += __shfl_xor(s1, mm, 64);
        s2 += __shfl_xor(s2, mm, 64);
    }
    float mean = s1 * (1.0f / 128.0f);
    float var  = s2 * (1.0f / 128.0f) - mean * mean;
    float rr   = rsqrtf(var + 1e-5f);
    float2 gg = ((const float2*)g)[lane];
    float2 bb = ((const float2*)be)[lane];
    float a0 = (ax - mean) * rr * gg.x + bb.x;
    float a1 = (ay - mean) * rr * gg.y + bb.y;
    a0 = a0 > 0.0f ? a0 : expm1f(a0);
    a1 = a1 > 0.0f ? a1 : expm1f(a1);
    if (xin) {
        float2 xi = ((const float2*)(xin + (size_t)node * DIM))[lane];
        a0 += xi.x;
        a1 += xi.y;
    }
    ((float2*)(out + (size_t)node * DIM))[lane] = make_float2(a0, a1);
}

// ---------------------------------------------------------------- MFMA classifier: out = X @ Wc + bc (no LDS)
// 3 n-tiles (48 cols, 40 valid). Lane (m,q): rows q*4+j, cols 3m..3m+2.
__global__ __launch_bounds__(256) void classifier_mfma(const float* __restrict__ X,
                                                       const unsigned short* __restrict__ Wcsw,
                                                       const float* __restrict__ bc,
                                                       float* __restrict__ out) {
    const int lane  = threadIdx.x & 63;
    const int wave  = threadIdx.x >> 6;
    const int row0w = blockIdx.x * 64 + wave * 16;
    const int m = lane & 15;
    const int q = lane >> 4;

    bf16x8 wf[12];
#pragma unroll
    for (int f = 0; f < 12; ++f)
        wf[f] = *(const bf16x8*)(Wcsw + (f << 9) + lane * 8);

    int r = row0w + m;
    if (r >= N_NODES) r = N_NODES - 1;
    const float* xp = X + (size_t)r * DIM + q * 8;
    bf16x8 af[4];
#pragma unroll
    for (int s = 0; s < 4; ++s) {
        float4 x0 = *(const float4*)(xp + s * 32);
        float4 x1 = *(const float4*)(xp + s * 32 + 4);
        union { bf16x8 v; unsigned u[4]; } t;
        t.u[0] = pack_bf2(x0.x, x0.y);
        t.u[1] = pack_bf2(x0.z, x0.w);
        t.u[2] = pack_bf2(x1.x, x1.y);
        t.u[3] = pack_bf2(x1.z, x1.w);
        af[s] = t.v;
    }

    f32x4 acc[3];
    f32x4 z = {0.f, 0.f, 0.f, 0.f};
#pragma unroll
    for (int n = 0; n < 3; ++n) acc[n] = z;

#pragma unroll
    for (int s = 0; s < 4; ++s)
#pragma unroll
        for (int n = 0; n < 3; ++n)
            acc[n] = __builtin_amdgcn_mfma_f32_16x16x32_bf16(af[s], wf[n * 4 + s], acc[n], 0, 0, 0);

    float bcv[3];
#pragma unroll
    for (int n = 0; n < 3; ++n) {
        int c = 3 * m + n;
        bcv[n] = (c < NCLS) ? bc[c] : 0.f;
    }

#pragma unroll
    for (int j = 0; j < 4; ++j) {
        int row = row0w + q * 4 + j;
        if (row < N_NODES) {
#pragma unroll
            for (int n = 0; n < 3; ++n) {
                int c = 3 * m + n;
                if (c < NCLS)
                    out[(size_t)row * NCLS + c] = acc[n][j] + bcv[n];
            }
        }
    }
}

// ---------------------------------------------------------------- launch
extern "C" void kernel_launch(void* const* d_in, const int* in_sizes, int n_in,
                              void* d_out, int out_size, void* d_ws, size_t ws_size,
                              hipStream_t stream) {
    const float* x  = (const float*)d_in[0];
    const int*   ei = (const int*)d_in[1];
    const float* W[3]  = {(const float*)d_in[2], (const float*)d_in[6], (const float*)d_in[10]};
    const float* b[3]  = {(const float*)d_in[3], (const float*)d_in[7], (const float*)d_in[11]};
    const float* g[3]  = {(const float*)d_in[4], (const float*)d_in[8], (const float*)d_in[12]};
    const float* be[3] = {(const float*)d_in[5], (const float*)d_in[9], (const float*)d_in[13]};
    const float* Wc = (const float*)d_in[14];
    const float* bc = (const float*)d_in[15];
    float* out = (float*)d_out;

    char* ws = (char*)d_ws;
    const size_t NP = 400128;  // padded N*4 bytes
    float* dinv   = (float*)(ws);
    int*   degi   = (int*)  (ws + NP);
    int*   rowptr = (int*)  (ws + 2 * NP);
    int*   ctr    = (int*)  (ws + 3 * NP);
    int*   bsums  = (int*)  (ws + 4 * NP);
    int2*  rec    = (int2*) (ws + 4 * NP + 512);
    unsigned short* Hb = (unsigned short*)(ws + 4 * NP + 512 + (size_t)N_EDGES * 8);
    float* A      = (float*)(ws + 4 * NP + 512 + (size_t)N_EDGES * 8 + (size_t)N_NODES * DIM * 2);
    float* C      = A + (size_t)N_NODES * DIM;
    unsigned short* Wsw0 = (unsigned short*)(C + (size_t)N_NODES * DIM);
    unsigned short* Wsw1 = Wsw0 + DIM * DIM;
    unsigned short* Wsw2 = Wsw1 + DIM * DIM;
    unsigned short* Wcsw = Wsw2 + DIM * DIM;   // 12*512 shorts

    // ---- W pre-swizzles (bf16, MFMA B-frag order) ----
    wswz<<<64, 256, 0, stream>>>(W[0], Wsw0);
    wswz<<<64, 256, 0, stream>>>(W[1], Wsw1);
    wswz<<<64, 256, 0, stream>>>(W[2], Wsw2);
    wcswz<<<24, 256, 0, stream>>>(Wc, Wcsw);

    // ---- CSR build ----
    hipMemsetAsync(degi, 0, N_NODES * sizeof(int), stream);
    deg_count<<<(N_EDGES + 255) / 256, 256, 0, stream>>>(ei, degi);
    finalize_dinv<<<(N_NODES + 255) / 256, 256, 0, stream>>>(degi, dinv);
    scan1<<<SCAN_BLOCKS, 256, 0, stream>>>(degi, rowptr, bsums);
    scan2<<<1, 128, 0, stream>>>(bsums);
    scan3<<<SCAN_BLOCKS * 4, 256, 0, stream>>>(rowptr, ctr, bsums);
    fill_csr<<<(N_EDGES + 255) / 256, 256, 0, stream>>>(ei, dinv, ctr, rec);

    const int gemm_grid = (N_NODES + 63) / 64;    // 1563
    const int agg_grid  = N_NODES / 4;            // 25000

    // layer 0
    gemm_mfma<<<gemm_grid, 256, 0, stream>>>(x, Wsw0, Hb);
    agg_ln<<<agg_grid, 256, 0, stream>>>(Hb, nullptr, dinv, b[0], g[0], be[0], rowptr, rec, C);

    // layer 1
    gemm_mfma<<<gemm_grid, 256, 0, stream>>>(C, Wsw1, Hb);
    agg_ln<<<agg_grid, 256, 0, stream>>>(Hb, C, dinv, b[1], g[1], be[1], rowptr, rec, A);

    // layer 2
    gemm_mfma<<<gemm_grid, 256, 0, stream>>>(A, Wsw2, Hb);
    agg_ln<<<agg_grid, 256, 0, stream>>>(Hb, A, dinv, b[2], g[2], be[2], rowptr, rec, C);

    classifier_mfma<<<gemm_grid, 256, 0, stream>>>(C, Wcsw, bc, out);
}

// Round 7
// 533.375 us; speedup vs baseline: 8.4666x; 1.0559x over previous
//
#include <hip/hip_runtime.h>
#include <math.h>

#define N_NODES 100000
#define N_EDGES 1600000
#define DIM     128
#define NCLS    40
#define SCAN_BLOCKS 98   // ceil(100000/1024)
#define NBUCK   196      // ceil(100000/512) buckets of 512 nodes
#define P1_CH   4096     // edges per phase-1 block
#define P1_GRID 391      // ceil(1600000/4096)

typedef __attribute__((ext_vector_type(8))) short bf16x8;
typedef __attribute__((ext_vector_type(4))) float f32x4;

// bf16 helpers (manual RNE; bf16->f32 is a shift)
__device__ inline unsigned short bf16r(float f) {
    unsigned u = __float_as_uint(f);
    unsigned r = (u + 0x7fffu + ((u >> 16) & 1u)) >> 16;
    return (unsigned short)r;
}
__device__ inline unsigned pack_bf2(float lo, float hi) {
    return (unsigned)bf16r(lo) | ((unsigned)bf16r(hi) << 16);
}
__device__ inline float bf_lo(unsigned v) { return __uint_as_float(v << 16); }
__device__ inline float bf_hi(unsigned v) { return __uint_as_float(v & 0xffff0000u); }

// ---------------------------------------------------------------- degree (int)
__global__ __launch_bounds__(256) void deg_count(const int* __restrict__ ei,
                                                 int* __restrict__ degi) {
    int e = blockIdx.x * 256 + threadIdx.x;
    if (e < N_EDGES) atomicAdd(&degi[ei[N_EDGES + e]], 1);
}

__global__ __launch_bounds__(256) void finalize_dinv(const int* __restrict__ degi,
                                                     float* __restrict__ dinv) {
    int n = blockIdx.x * 256 + threadIdx.x;
    if (n < N_NODES) dinv[n] = rsqrtf((float)degi[n] + 1.0f);
}

// ---------------------------------------------------------------- scan (exclusive) over degi -> rowptr
__global__ __launch_bounds__(256) void scan1(const int* __restrict__ degi,
                                             int* __restrict__ rowptr,
                                             int* __restrict__ bsums) {
    __shared__ int sums[256];
    int t    = threadIdx.x;
    int base = blockIdx.x * 1024 + t * 4;
    int v[4], s = 0;
#pragma unroll
    for (int i = 0; i < 4; ++i) {
        int idx = base + i;
        v[i] = (idx < N_NODES) ? degi[idx] : 0;
        s += v[i];
    }
    sums[t] = s;
    __syncthreads();
    for (int off = 1; off < 256; off <<= 1) {
        int x = (t >= off) ? sums[t - off] : 0;
        __syncthreads();
        sums[t] += x;
        __syncthreads();
    }
    int run = (t == 0) ? 0 : sums[t - 1];
#pragma unroll
    for (int i = 0; i < 4; ++i) {
        int idx = base + i;
        if (idx < N_NODES) rowptr[idx] = run;
        run += v[i];
    }
    if (t == 255) bsums[blockIdx.x] = sums[255];
}

__global__ __launch_bounds__(128) void scan2(int* __restrict__ bsums) {
    __shared__ int s[128];
    int t = threadIdx.x;
    s[t] = (t < SCAN_BLOCKS) ? bsums[t] : 0;
    __syncthreads();
    for (int off = 1; off < 128; off <<= 1) {
        int x = (t >= off) ? s[t - off] : 0;
        __syncthreads();
        s[t] += x;
        __syncthreads();
    }
    if (t < SCAN_BLOCKS) bsums[t] = (t == 0) ? 0 : s[t - 1];
}

__global__ __launch_bounds__(256) void scan3(int* __restrict__ rowptr,
                                             int* __restrict__ bcur,
                                             const int* __restrict__ bsums) {
    int idx = blockIdx.x * 256 + threadIdx.x;
    if (idx < N_NODES) {
        int v = rowptr[idx] + bsums[idx >> 10];
        rowptr[idx] = v;
        if ((idx & 511) == 0) bcur[idx >> 9] = v;   // bucket base cursor
    }
    if (idx == 0) rowptr[N_NODES] = N_EDGES;
}

// ---------------------------------------------------------------- phase 1: bucket edges by dst>>9 into tmp (coalesced runs)
__global__ __launch_bounds__(256) void bucket_p1(const int* __restrict__ ei,
                                                 int* __restrict__ bcur,
                                                 int2* __restrict__ tmp) {
    __shared__ int  hist[256];
    __shared__ int  lscan[256];
    __shared__ int  rank[256];
    __shared__ int  gbase[256];
    __shared__ int2 stage[P1_CH];      // 32 KB
    const int t  = threadIdx.x;
    const int e0 = blockIdx.x * P1_CH;
    const int cnt = min(P1_CH, N_EDGES - e0);

    hist[t] = 0;
    __syncthreads();

    int2 ed[16];
#pragma unroll
    for (int i = 0; i < 16; ++i) {
        int idx = t + i * 256;
        if (idx < cnt) {
            int s = ei[e0 + idx];
            int d = ei[N_EDGES + e0 + idx];
            ed[i] = make_int2(s, d);
            atomicAdd(&hist[d >> 9], 1);
        }
    }
    __syncthreads();

    // exclusive scan of hist (Hillis-Steele over 256)
    int hv = hist[t];
    lscan[t] = hv;
    __syncthreads();
    for (int off = 1; off < 256; off <<= 1) {
        int x = (t >= off) ? lscan[t - off] : 0;
        __syncthreads();
        lscan[t] += x;
        __syncthreads();
    }
    int excl = (t == 0) ? 0 : lscan[t - 1];
    __syncthreads();
    lscan[t] = excl;
    rank[t]  = excl;
    if (hv > 0) gbase[t] = atomicAdd(&bcur[t], hv);
    __syncthreads();

    // place edges into stage, sorted by bucket
#pragma unroll
    for (int i = 0; i < 16; ++i) {
        int idx = t + i * 256;
        if (idx < cnt) {
            int b = ed[i].y >> 9;
            int p = atomicAdd(&rank[b], 1);
            stage[p] = ed[i];
        }
    }
    __syncthreads();

    // copy out: per-bucket contiguous runs -> coalesced global writes
    for (int p = t; p < cnt; p += 256) {
        int2 v = stage[p];
        int b = v.y >> 9;
        tmp[gbase[b] + (p - lscan[b])] = v;
    }
}

// ---------------------------------------------------------------- phase 2: within-bucket scatter to final CSR slots (LDS cursors)
__global__ __launch_bounds__(256) void bucket_p2(const int2* __restrict__ tmp,
                                                 const int* __restrict__ rowptr,
                                                 const float* __restrict__ dinv,
                                                 int2* __restrict__ rec) {
    __shared__ int cur[512];
    const int t  = threadIdx.x;
    const int b  = blockIdx.x;
    const int d0 = b << 9;
    const int dend = min(d0 + 512, N_NODES);
    const int nn = dend - d0;

    for (int i = t; i < nn; i += 256) cur[i] = rowptr[d0 + i];
    __syncthreads();

    const int beg = rowptr[d0];
    const int end = rowptr[dend];
    for (int idx = beg + t; idx < end; idx += 256) {
        int2 v = tmp[idx];
        int s = v.x, d = v.y;
        int pos = atomicAdd(&cur[d - d0], 1);
        rec[pos] = make_int2(s, __float_as_int(dinv[s] * dinv[d]));
    }
}

// ---------------------------------------------------------------- W pre-swizzle into MFMA B-fragment order (bf16)
__global__ __launch_bounds__(256) void wswz(const float* __restrict__ W,
                                            unsigned short* __restrict__ Wsw) {
    int o = blockIdx.x * 256 + threadIdx.x;      // 0..16383
    int f = o >> 9;
    int l = (o >> 3) & 63;
    int j = o & 7;
    int n = f >> 2;
    int s = f & 3;
    int k = s * 32 + (l >> 4) * 8 + j;
    int c = (l & 15) * 8 + n;
    Wsw[o] = bf16r(W[k * DIM + c]);
}

// ---------------------------------------------------------------- Wc pre-swizzle (128x40 -> 3 n-tiles, c = 3m+n)
__global__ __launch_bounds__(256) void wcswz(const float* __restrict__ Wc,
                                             unsigned short* __restrict__ Wcsw) {
    int o = blockIdx.x * 256 + threadIdx.x;      // 0..6143
    if (o >= 12 * 512) return;
    int f = o >> 9;
    int l = (o >> 3) & 63;
    int j = o & 7;
    int n = f >> 2;
    int s = f & 3;
    int k = s * 32 + (l >> 4) * 8 + j;
    int c = (l & 15) * 3 + n;
    Wcsw[o] = (c < NCLS) ? bf16r(Wc[k * NCLS + c]) : (unsigned short)0;
}

// ---------------------------------------------------------------- MFMA GEMM: H(bf16) = X(fp32) @ W  (K=128, no LDS)
__global__ __launch_bounds__(256, 2) void gemm_mfma(const float* __restrict__ X,
                                                    const unsigned short* __restrict__ Wsw,
                                                    unsigned short* __restrict__ H) {
    const int lane  = threadIdx.x & 63;
    const int wave  = threadIdx.x >> 6;
    const int row0w = blockIdx.x * 64 + wave * 16;
    const int m = lane & 15;
    const int q = lane >> 4;

    bf16x8 wf[32];
#pragma unroll
    for (int f = 0; f < 32; ++f)
        wf[f] = *(const bf16x8*)(Wsw + (f << 9) + lane * 8);

    int r = row0w + m;
    if (r >= N_NODES) r = N_NODES - 1;           // clamp; stores guarded
    const float* xp = X + (size_t)r * DIM + q * 8;
    float4 xa[8];
#pragma unroll
    for (int s = 0; s < 4; ++s) {
        xa[2 * s]     = *(const float4*)(xp + s * 32);
        xa[2 * s + 1] = *(const float4*)(xp + s * 32 + 4);
    }
    bf16x8 af[4];
#pragma unroll
    for (int s = 0; s < 4; ++s) {
        union { bf16x8 v; unsigned u[4]; } t;
        t.u[0] = pack_bf2(xa[2 * s].x, xa[2 * s].y);
        t.u[1] = pack_bf2(xa[2 * s].z, xa[2 * s].w);
        t.u[2] = pack_bf2(xa[2 * s + 1].x, xa[2 * s + 1].y);
        t.u[3] = pack_bf2(xa[2 * s + 1].z, xa[2 * s + 1].w);
        af[s] = t.v;
    }

    f32x4 acc[8];
    f32x4 z = {0.f, 0.f, 0.f, 0.f};
#pragma unroll
    for (int n = 0; n < 8; ++n) acc[n] = z;

#pragma unroll
    for (int s = 0; s < 4; ++s)
#pragma unroll
        for (int n = 0; n < 8; ++n)
            acc[n] = __builtin_amdgcn_mfma_f32_16x16x32_bf16(af[s], wf[n * 4 + s], acc[n], 0, 0, 0);

#pragma unroll
    for (int j = 0; j < 4; ++j) {
        int row = row0w + q * 4 + j;
        if (row < N_NODES) {
            int4 o = make_int4((int)pack_bf2(acc[0][j], acc[1][j]),
                               (int)pack_bf2(acc[2][j], acc[3][j]),
                               (int)pack_bf2(acc[4][j], acc[5][j]),
                               (int)pack_bf2(acc[6][j], acc[7][j]));
            *(int4*)(H + (size_t)row * DIM + m * 8) = o;
        }
    }
}

// ---------------------------------------------------------------- fused gather-aggregate + LN + ELU (+ residual)
__global__ __launch_bounds__(256) void agg_ln(const unsigned short* __restrict__ Hb,
                                              const float* __restrict__ xin,
                                              const float* __restrict__ dinv,
                                              const float* __restrict__ bias,
                                              const float* __restrict__ g,
                                              const float* __restrict__ be,
                                              const int* __restrict__ rowptr,
                                              const int2* __restrict__ rec,
                                              float* __restrict__ out) {
    int node = blockIdx.x * 4 + (threadIdx.x >> 6);
    int lane = threadIdx.x & 63;
    int beg = rowptr[node];
    int end = rowptr[node + 1];

    float dv = dinv[node];
    float d2 = dv * dv;
    unsigned hv = ((const unsigned*)(Hb + (size_t)node * DIM))[lane];
    float2 bv = ((const float2*)bias)[lane];
    float ax = bf_lo(hv) * d2 + bv.x;
    float ay = bf_hi(hv) * d2 + bv.y;

    for (int e0 = beg; e0 < end; e0 += 64) {
        int cnt = end - e0;
        if (cnt > 64) cnt = 64;
        int2 rc = (lane < cnt) ? rec[e0 + lane] : make_int2(0, 0);
        int   sv = rc.x;
        float wv = __int_as_float(rc.y);
        int j = 0;
        for (; j + 3 < cnt; j += 4) {
            int   s0 = __shfl(sv, j, 64),     s1 = __shfl(sv, j + 1, 64);
            int   s2 = __shfl(sv, j + 2, 64), s3 = __shfl(sv, j + 3, 64);
            float w0 = __shfl(wv, j, 64),     w1 = __shfl(wv, j + 1, 64);
            float w2 = __shfl(wv, j + 2, 64), w3 = __shfl(wv, j + 3, 64);
            unsigned u0 = ((const unsigned*)(Hb + (size_t)s0 * DIM))[lane];
            unsigned u1 = ((const unsigned*)(Hb + (size_t)s1 * DIM))[lane];
            unsigned u2 = ((const unsigned*)(Hb + (size_t)s2 * DIM))[lane];
            unsigned u3 = ((const unsigned*)(Hb + (size_t)s3 * DIM))[lane];
            ax += bf_lo(u0) * w0 + bf_lo(u1) * w1 + bf_lo(u2) * w2 + bf_lo(u3) * w3;
            ay += bf_hi(u0) * w0 + bf_hi(u1) * w1 + bf_hi(u2) * w2 + bf_hi(u3) * w3;
        }
        for (; j < cnt; ++j) {
            int   s0 = __shfl(sv, j, 64);
            float w0 = __shfl(wv, j, 64);
            unsigned u0 = ((const unsigned*)(Hb + (size_t)s0 * DIM))[lane];
            ax += bf_lo(u0) * w0;
            ay += bf_hi(u0) * w0;
        }
    }

    float s1 = ax + ay;
    float s2 = ax * ax + ay * ay;
#pragma unroll
    for (int mm = 1; mm < 64; mm <<= 1) {
        s1 += __shfl_xor(s1, mm, 64);
        s2 += __shfl_xor(s2, mm, 64);
    }
    float mean = s1 * (1.0f / 128.0f);
    float var  = s2 * (1.0f / 128.0f) - mean * mean;
    float rr   = rsqrtf(var + 1e-5f);
    float2 gg = ((const float2*)g)[lane];
    float2 bb = ((const float2*)be)[lane];
    float a0 = (ax - mean) * rr * gg.x + bb.x;
    float a1 = (ay - mean) * rr * gg.y + bb.y;
    a0 = a0 > 0.0f ? a0 : expm1f(a0);
    a1 = a1 > 0.0f ? a1 : expm1f(a1);
    if (xin) {
        float2 xi = ((const float2*)(xin + (size_t)node * DIM))[lane];
        a0 += xi.x;
        a1 += xi.y;
    }
    ((float2*)(out + (size_t)node * DIM))[lane] = make_float2(a0, a1);
}

// ---------------------------------------------------------------- MFMA classifier: out = X @ Wc + bc (no LDS)
__global__ __launch_bounds__(256) void classifier_mfma(const float* __restrict__ X,
                                                       const unsigned short* __restrict__ Wcsw,
                                                       const float* __restrict__ bc,
                                                       float* __restrict__ out) {
    const int lane  = threadIdx.x & 63;
    const int wave  = threadIdx.x >> 6;
    const int row0w = blockIdx.x * 64 + wave * 16;
    const int m = lane & 15;
    const int q = lane >> 4;

    bf16x8 wf[12];
#pragma unroll
    for (int f = 0; f < 12; ++f)
        wf[f] = *(const bf16x8*)(Wcsw + (f << 9) + lane * 8);

    int r = row0w + m;
    if (r >= N_NODES) r = N_NODES - 1;
    const float* xp = X + (size_t)r * DIM + q * 8;
    bf16x8 af[4];
#pragma unroll
    for (int s = 0; s < 4; ++s) {
        float4 x0 = *(const float4*)(xp + s * 32);
        float4 x1 = *(const float4*)(xp + s * 32 + 4);
        union { bf16x8 v; unsigned u[4]; } t;
        t.u[0] = pack_bf2(x0.x, x0.y);
        t.u[1] = pack_bf2(x0.z, x0.w);
        t.u[2] = pack_bf2(x1.x, x1.y);
        t.u[3] = pack_bf2(x1.z, x1.w);
        af[s] = t.v;
    }

    f32x4 acc[3];
    f32x4 z = {0.f, 0.f, 0.f, 0.f};
#pragma unroll
    for (int n = 0; n < 3; ++n) acc[n] = z;

#pragma unroll
    for (int s = 0; s < 4; ++s)
#pragma unroll
        for (int n = 0; n < 3; ++n)
            acc[n] = __builtin_amdgcn_mfma_f32_16x16x32_bf16(af[s], wf[n * 4 + s], acc[n], 0, 0, 0);

    float bcv[3];
#pragma unroll
    for (int n = 0; n < 3; ++n) {
        int c = 3 * m + n;
        bcv[n] = (c < NCLS) ? bc[c] : 0.f;
    }

#pragma unroll
    for (int j = 0; j < 4; ++j) {
        int row = row0w + q * 4 + j;
        if (row < N_NODES) {
#pragma unroll
            for (int n = 0; n < 3; ++n) {
                int c = 3 * m + n;
                if (c < NCLS)
                    out[(size_t)row * NCLS + c] = acc[n][j] + bcv[n];
            }
        }
    }
}

// ---------------------------------------------------------------- launch
extern "C" void kernel_launch(void* const* d_in, const int* in_sizes, int n_in,
                              void* d_out, int out_size, void* d_ws, size_t ws_size,
                              hipStream_t stream) {
    const float* x  = (const float*)d_in[0];
    const int*   ei = (const int*)d_in[1];
    const float* W[3]  = {(const float*)d_in[2], (const float*)d_in[6], (const float*)d_in[10]};
    const float* b[3]  = {(const float*)d_in[3], (const float*)d_in[7], (const float*)d_in[11]};
    const float* g[3]  = {(const float*)d_in[4], (const float*)d_in[8], (const float*)d_in[12]};
    const float* be[3] = {(const float*)d_in[5], (const float*)d_in[9], (const float*)d_in[13]};
    const float* Wc = (const float*)d_in[14];
    const float* bc = (const float*)d_in[15];
    float* out = (float*)d_out;

    char* ws = (char*)d_ws;
    const size_t NP = 400128;  // padded N*4 bytes
    float* dinv   = (float*)(ws);
    int*   degi   = (int*)  (ws + NP);
    int*   rowptr = (int*)  (ws + 2 * NP);
    int*   bcur   = (int*)  (ws + 3 * NP);
    int*   bsums  = (int*)  (ws + 4 * NP);
    int2*  rec    = (int2*) (ws + 4 * NP + 512);
    unsigned short* Hb = (unsigned short*)(ws + 4 * NP + 512 + (size_t)N_EDGES * 8);
    float* A      = (float*)(ws + 4 * NP + 512 + (size_t)N_EDGES * 8 + (size_t)N_NODES * DIM * 2);
    float* C      = A + (size_t)N_NODES * DIM;
    unsigned short* Wsw0 = (unsigned short*)(C + (size_t)N_NODES * DIM);
    unsigned short* Wsw1 = Wsw0 + DIM * DIM;
    unsigned short* Wsw2 = Wsw1 + DIM * DIM;
    unsigned short* Wcsw = Wsw2 + DIM * DIM;   // 12*512 shorts
    int2*  tmp    = (int2*)C;                  // aliases C; dead before layer 0 writes C

    // ---- W pre-swizzles (bf16, MFMA B-frag order) ----
    wswz<<<64, 256, 0, stream>>>(W[0], Wsw0);
    wswz<<<64, 256, 0, stream>>>(W[1], Wsw1);
    wswz<<<64, 256, 0, stream>>>(W[2], Wsw2);
    wcswz<<<24, 256, 0, stream>>>(Wc, Wcsw);

    // ---- CSR build ----
    hipMemsetAsync(degi, 0, N_NODES * sizeof(int), stream);
    deg_count<<<(N_EDGES + 255) / 256, 256, 0, stream>>>(ei, degi);
    finalize_dinv<<<(N_NODES + 255) / 256, 256, 0, stream>>>(degi, dinv);
    scan1<<<SCAN_BLOCKS, 256, 0, stream>>>(degi, rowptr, bsums);
    scan2<<<1, 128, 0, stream>>>(bsums);
    scan3<<<SCAN_BLOCKS * 4, 256, 0, stream>>>(rowptr, bcur, bsums);
    bucket_p1<<<P1_GRID, 256, 0, stream>>>(ei, bcur, tmp);
    bucket_p2<<<NBUCK, 256, 0, stream>>>(tmp, rowptr, dinv, rec);

    const int gemm_grid = (N_NODES + 63) / 64;    // 1563
    const int agg_grid  = N_NODES / 4;            // 25000

    // layer 0
    gemm_mfma<<<gemm_grid, 256, 0, stream>>>(x, Wsw0, Hb);
    agg_ln<<<agg_grid, 256, 0, stream>>>(Hb, nullptr, dinv, b[0], g[0], be[0], rowptr, rec, C);

    // layer 1
    gemm_mfma<<<gemm_grid, 256, 0, stream>>>(C, Wsw1, Hb);
    agg_ln<<<agg_grid, 256, 0, stream>>>(Hb, C, dinv, b[1], g[1], be[1], rowptr, rec, A);

    // layer 2
    gemm_mfma<<<gemm_grid, 256, 0, stream>>>(A, Wsw2, Hb);
    agg_ln<<<agg_grid, 256, 0, stream>>>(Hb, A, dinv, b[2], g[2], be[2], rowptr, rec, C);

    classifier_mfma<<<gemm_grid, 256, 0, stream>>>(C, Wcsw, bc, out);
}

// Round 8
// 496.313 us; speedup vs baseline: 9.0989x; 1.0747x over previous
//
#include <hip/hip_runtime.h>
#include <math.h>

#define N_NODES 100000
#define N_EDGES 1600000
#define DIM     128
#define NCLS    40
#define SCAN_BLOCKS 98   // ceil(100000/1024)
#define NBUCK   196      // ceil(100000/512) buckets of 512 nodes
#define P1_CH   4096     // edges per phase-1 block
#define P1_GRID 391      // ceil(1600000/4096)

typedef __attribute__((ext_vector_type(8))) short bf16x8;
typedef __attribute__((ext_vector_type(4))) float f32x4;

// bf16 helpers (manual RNE; bf16->f32 is a shift)
__device__ inline unsigned short bf16r(float f) {
    unsigned u = __float_as_uint(f);
    unsigned r = (u + 0x7fffu + ((u >> 16) & 1u)) >> 16;
    return (unsigned short)r;
}
__device__ inline unsigned pack_bf2(float lo, float hi) {
    return (unsigned)bf16r(lo) | ((unsigned)bf16r(hi) << 16);
}
__device__ inline float bf_lo(unsigned v) { return __uint_as_float(v << 16); }
__device__ inline float bf_hi(unsigned v) { return __uint_as_float(v & 0xffff0000u); }

// ---------------------------------------------------------------- degree (int)
__global__ __launch_bounds__(256) void deg_count(const int* __restrict__ ei,
                                                 int* __restrict__ degi) {
    int e = blockIdx.x * 256 + threadIdx.x;
    if (e < N_EDGES) atomicAdd(&degi[ei[N_EDGES + e]], 1);
}

__global__ __launch_bounds__(256) void finalize_dinv(const int* __restrict__ degi,
                                                     float* __restrict__ dinv) {
    int n = blockIdx.x * 256 + threadIdx.x;
    if (n < N_NODES) dinv[n] = rsqrtf((float)degi[n] + 1.0f);
}

// ---------------------------------------------------------------- scan (exclusive) over degi -> rowptr
__global__ __launch_bounds__(256) void scan1(const int* __restrict__ degi,
                                             int* __restrict__ rowptr,
                                             int* __restrict__ bsums) {
    __shared__ int sums[256];
    int t    = threadIdx.x;
    int base = blockIdx.x * 1024 + t * 4;
    int v[4], s = 0;
#pragma unroll
    for (int i = 0; i < 4; ++i) {
        int idx = base + i;
        v[i] = (idx < N_NODES) ? degi[idx] : 0;
        s += v[i];
    }
    sums[t] = s;
    __syncthreads();
    for (int off = 1; off < 256; off <<= 1) {
        int x = (t >= off) ? sums[t - off] : 0;
        __syncthreads();
        sums[t] += x;
        __syncthreads();
    }
    int run = (t == 0) ? 0 : sums[t - 1];
#pragma unroll
    for (int i = 0; i < 4; ++i) {
        int idx = base + i;
        if (idx < N_NODES) rowptr[idx] = run;
        run += v[i];
    }
    if (t == 255) bsums[blockIdx.x] = sums[255];
}

__global__ __launch_bounds__(128) void scan2(int* __restrict__ bsums) {
    __shared__ int s[128];
    int t = threadIdx.x;
    s[t] = (t < SCAN_BLOCKS) ? bsums[t] : 0;
    __syncthreads();
    for (int off = 1; off < 128; off <<= 1) {
        int x = (t >= off) ? s[t - off] : 0;
        __syncthreads();
        s[t] += x;
        __syncthreads();
    }
    if (t < SCAN_BLOCKS) bsums[t] = (t == 0) ? 0 : s[t - 1];
}

__global__ __launch_bounds__(256) void scan3(int* __restrict__ rowptr,
                                             int* __restrict__ bcur,
                                             const int* __restrict__ bsums) {
    int idx = blockIdx.x * 256 + threadIdx.x;
    if (idx < N_NODES) {
        int v = rowptr[idx] + bsums[idx >> 10];
        rowptr[idx] = v;
        if ((idx & 511) == 0) bcur[idx >> 9] = v;   // bucket base cursor
    }
    if (idx == 0) rowptr[N_NODES] = N_EDGES;
}

// ---------------------------------------------------------------- phase 1: bucket edges by dst>>9 into tmp (coalesced runs)
__global__ __launch_bounds__(256) void bucket_p1(const int* __restrict__ ei,
                                                 int* __restrict__ bcur,
                                                 int2* __restrict__ tmp) {
    __shared__ int  hist[256];
    __shared__ int  lscan[256];
    __shared__ int  rank[256];
    __shared__ int  gbase[256];
    __shared__ int2 stage[P1_CH];      // 32 KB
    const int t  = threadIdx.x;
    const int e0 = blockIdx.x * P1_CH;
    const int cnt = min(P1_CH, N_EDGES - e0);

    hist[t] = 0;
    __syncthreads();

    int2 ed[16];
#pragma unroll
    for (int i = 0; i < 16; ++i) {
        int idx = t + i * 256;
        if (idx < cnt) {
            int s = ei[e0 + idx];
            int d = ei[N_EDGES + e0 + idx];
            ed[i] = make_int2(s, d);
            atomicAdd(&hist[d >> 9], 1);
        }
    }
    __syncthreads();

    int hv = hist[t];
    lscan[t] = hv;
    __syncthreads();
    for (int off = 1; off < 256; off <<= 1) {
        int x = (t >= off) ? lscan[t - off] : 0;
        __syncthreads();
        lscan[t] += x;
        __syncthreads();
    }
    int excl = (t == 0) ? 0 : lscan[t - 1];
    __syncthreads();
    lscan[t] = excl;
    rank[t]  = excl;
    if (hv > 0) gbase[t] = atomicAdd(&bcur[t], hv);
    __syncthreads();

#pragma unroll
    for (int i = 0; i < 16; ++i) {
        int idx = t + i * 256;
        if (idx < cnt) {
            int b = ed[i].y >> 9;
            int p = atomicAdd(&rank[b], 1);
            stage[p] = ed[i];
        }
    }
    __syncthreads();

    for (int p = t; p < cnt; p += 256) {
        int2 v = stage[p];
        int b = v.y >> 9;
        tmp[gbase[b] + (p - lscan[b])] = v;
    }
}

// ---------------------------------------------------------------- phase 2: within-bucket scatter to final CSR slots (LDS cursors)
__global__ __launch_bounds__(256) void bucket_p2(const int2* __restrict__ tmp,
                                                 const int* __restrict__ rowptr,
                                                 const float* __restrict__ dinv,
                                                 int2* __restrict__ rec) {
    __shared__ int cur[512];
    const int t  = threadIdx.x;
    const int b  = blockIdx.x;
    const int d0 = b << 9;
    const int dend = min(d0 + 512, N_NODES);
    const int nn = dend - d0;

    for (int i = t; i < nn; i += 256) cur[i] = rowptr[d0 + i];
    __syncthreads();

    const int beg = rowptr[d0];
    const int end = rowptr[dend];
    for (int idx = beg + t; idx < end; idx += 256) {
        int2 v = tmp[idx];
        int s = v.x, d = v.y;
        int pos = atomicAdd(&cur[d - d0], 1);
        rec[pos] = make_int2(s, __float_as_int(dinv[s] * dinv[d]));
    }
}

// ---------------------------------------------------------------- W pre-swizzle into MFMA B-fragment order (bf16)
__global__ __launch_bounds__(256) void wswz(const float* __restrict__ W,
                                            unsigned short* __restrict__ Wsw) {
    int o = blockIdx.x * 256 + threadIdx.x;      // 0..16383
    int f = o >> 9;
    int l = (o >> 3) & 63;
    int j = o & 7;
    int n = f >> 2;
    int s = f & 3;
    int k = s * 32 + (l >> 4) * 8 + j;
    int c = (l & 15) * 8 + n;
    Wsw[o] = bf16r(W[k * DIM + c]);
}

// ---------------------------------------------------------------- Wc pre-swizzle (128x40 -> 3 n-tiles, c = 3m+n)
__global__ __launch_bounds__(256) void wcswz(const float* __restrict__ Wc,
                                             unsigned short* __restrict__ Wcsw) {
    int o = blockIdx.x * 256 + threadIdx.x;      // 0..6143
    if (o >= 12 * 512) return;
    int f = o >> 9;
    int l = (o >> 3) & 63;
    int j = o & 7;
    int n = f >> 2;
    int s = f & 3;
    int k = s * 32 + (l >> 4) * 8 + j;
    int c = (l & 15) * 3 + n;
    Wcsw[o] = (c < NCLS) ? bf16r(Wc[k * NCLS + c]) : (unsigned short)0;
}

// ---------------------------------------------------------------- MFMA GEMM, fp32 input (layer 0): H(bf16) = X @ W
__global__ __launch_bounds__(256, 2) void gemm_mfma_f(const float* __restrict__ X,
                                                      const unsigned short* __restrict__ Wsw,
                                                      unsigned short* __restrict__ H) {
    const int lane  = threadIdx.x & 63;
    const int wave  = threadIdx.x >> 6;
    const int row0w = blockIdx.x * 64 + wave * 16;
    const int m = lane & 15;
    const int q = lane >> 4;

    bf16x8 wf[32];
#pragma unroll
    for (int f = 0; f < 32; ++f)
        wf[f] = *(const bf16x8*)(Wsw + (f << 9) + lane * 8);

    int r = row0w + m;
    if (r >= N_NODES) r = N_NODES - 1;
    const float* xp = X + (size_t)r * DIM + q * 8;
    bf16x8 af[4];
#pragma unroll
    for (int s = 0; s < 4; ++s) {
        float4 x0 = *(const float4*)(xp + s * 32);
        float4 x1 = *(const float4*)(xp + s * 32 + 4);
        union { bf16x8 v; unsigned u[4]; } t;
        t.u[0] = pack_bf2(x0.x, x0.y);
        t.u[1] = pack_bf2(x0.z, x0.w);
        t.u[2] = pack_bf2(x1.x, x1.y);
        t.u[3] = pack_bf2(x1.z, x1.w);
        af[s] = t.v;
    }

    f32x4 acc[8];
    f32x4 z = {0.f, 0.f, 0.f, 0.f};
#pragma unroll
    for (int n = 0; n < 8; ++n) acc[n] = z;

#pragma unroll
    for (int s = 0; s < 4; ++s)
#pragma unroll
        for (int n = 0; n < 8; ++n)
            acc[n] = __builtin_amdgcn_mfma_f32_16x16x32_bf16(af[s], wf[n * 4 + s], acc[n], 0, 0, 0);

#pragma unroll
    for (int j = 0; j < 4; ++j) {
        int row = row0w + q * 4 + j;
        if (row < N_NODES) {
            int4 o = make_int4((int)pack_bf2(acc[0][j], acc[1][j]),
                               (int)pack_bf2(acc[2][j], acc[3][j]),
                               (int)pack_bf2(acc[4][j], acc[5][j]),
                               (int)pack_bf2(acc[6][j], acc[7][j]));
            *(int4*)(H + (size_t)row * DIM + m * 8) = o;
        }
    }
}

// ---------------------------------------------------------------- MFMA GEMM, bf16 input (layers 1,2): direct 16B A-frag loads
__global__ __launch_bounds__(256, 2) void gemm_mfma_b(const unsigned short* __restrict__ Xb,
                                                      const unsigned short* __restrict__ Wsw,
                                                      unsigned short* __restrict__ H) {
    const int lane  = threadIdx.x & 63;
    const int wave  = threadIdx.x >> 6;
    const int row0w = blockIdx.x * 64 + wave * 16;
    const int m = lane & 15;
    const int q = lane >> 4;

    bf16x8 wf[32];
#pragma unroll
    for (int f = 0; f < 32; ++f)
        wf[f] = *(const bf16x8*)(Wsw + (f << 9) + lane * 8);

    int r = row0w + m;
    if (r >= N_NODES) r = N_NODES - 1;
    const unsigned short* xp = Xb + (size_t)r * DIM + q * 8;
    bf16x8 af[4];
#pragma unroll
    for (int s = 0; s < 4; ++s) af[s] = *(const bf16x8*)(xp + s * 32);

    f32x4 acc[8];
    f32x4 z = {0.f, 0.f, 0.f, 0.f};
#pragma unroll
    for (int n = 0; n < 8; ++n) acc[n] = z;

#pragma unroll
    for (int s = 0; s < 4; ++s)
#pragma unroll
        for (int n = 0; n < 8; ++n)
            acc[n] = __builtin_amdgcn_mfma_f32_16x16x32_bf16(af[s], wf[n * 4 + s], acc[n], 0, 0, 0);

#pragma unroll
    for (int j = 0; j < 4; ++j) {
        int row = row0w + q * 4 + j;
        if (row < N_NODES) {
            int4 o = make_int4((int)pack_bf2(acc[0][j], acc[1][j]),
                               (int)pack_bf2(acc[2][j], acc[3][j]),
                               (int)pack_bf2(acc[4][j], acc[5][j]),
                               (int)pack_bf2(acc[6][j], acc[7][j]));
            *(int4*)(H + (size_t)row * DIM + m * 8) = o;
        }
    }
}

// ---------------------------------------------------------------- fused gather-aggregate + LN + ELU (+ residual), bf16 in/out
// One wave per node. Lane = (half = lane>>5, sub = lane&31). Each lane owns
// 4 cols (sub*4..+3, 8B bf16). One dwordx2 wave-load serves 2 edges (halves
// process different edges); shfl index is per-lane (j + half) -> 1 bpermute.
__global__ __launch_bounds__(256) void agg_ln(const unsigned short* __restrict__ Hb,
                                              const unsigned short* __restrict__ xin,
                                              const float* __restrict__ dinv,
                                              const float* __restrict__ bias,
                                              const float* __restrict__ g,
                                              const float* __restrict__ be,
                                              const int* __restrict__ rowptr,
                                              const int2* __restrict__ rec,
                                              unsigned short* __restrict__ outb) {
    int node = blockIdx.x * 4 + (threadIdx.x >> 6);
    int lane = threadIdx.x & 63;
    int sub  = lane & 31;
    int half = lane >> 5;
    int beg = rowptr[node];
    int end = rowptr[node + 1];

    float4 bv = ((const float4*)bias)[sub];
    float dv = dinv[node];
    float d2 = dv * dv;
    uint2 hv = *(const uint2*)(Hb + (size_t)node * DIM + sub * 4);
    float a0, a1, a2, a3;
    if (half == 0) {
        a0 = bf_lo(hv.x) * d2 + bv.x;
        a1 = bf_hi(hv.x) * d2 + bv.y;
        a2 = bf_lo(hv.y) * d2 + bv.z;
        a3 = bf_hi(hv.y) * d2 + bv.w;
    } else {
        a0 = a1 = a2 = a3 = 0.f;
    }

    for (int e0 = beg; e0 < end; e0 += 64) {
        int cnt = min(end - e0, 64);
        int2 rc = (lane < cnt) ? rec[e0 + lane] : make_int2(0, 0);
        int   sv = rc.x;
        float wv = __int_as_float(rc.y);
        int cntR = (cnt + 7) & ~7;
        for (int j = 0; j < cntR; j += 8) {
            int   iA = j + half,     iB = j + 2 + half;
            int   iC = j + 4 + half, iD = j + 6 + half;
            int   sA = __shfl(sv, iA, 64); float wA = __shfl(wv, iA, 64);
            int   sB = __shfl(sv, iB, 64); float wB = __shfl(wv, iB, 64);
            int   sC = __shfl(sv, iC, 64); float wC = __shfl(wv, iC, 64);
            int   sD = __shfl(sv, iD, 64); float wD = __shfl(wv, iD, 64);
            uint2 uA = *(const uint2*)(Hb + (size_t)sA * DIM + sub * 4);
            uint2 uB = *(const uint2*)(Hb + (size_t)sB * DIM + sub * 4);
            uint2 uC = *(const uint2*)(Hb + (size_t)sC * DIM + sub * 4);
            uint2 uD = *(const uint2*)(Hb + (size_t)sD * DIM + sub * 4);
            a0 += bf_lo(uA.x) * wA + bf_lo(uB.x) * wB + bf_lo(uC.x) * wC + bf_lo(uD.x) * wD;
            a1 += bf_hi(uA.x) * wA + bf_hi(uB.x) * wB + bf_hi(uC.x) * wC + bf_hi(uD.x) * wD;
            a2 += bf_lo(uA.y) * wA + bf_lo(uB.y) * wB + bf_lo(uC.y) * wC + bf_lo(uD.y) * wD;
            a3 += bf_hi(uA.y) * wA + bf_hi(uB.y) * wB + bf_hi(uC.y) * wC + bf_hi(uD.y) * wD;
        }
    }

    // merge halves (both halves end with full per-col sums)
    a0 += __shfl_xor(a0, 32, 64);
    a1 += __shfl_xor(a1, 32, 64);
    a2 += __shfl_xor(a2, 32, 64);
    a3 += __shfl_xor(a3, 32, 64);

    // LN reduction across 32 sublanes (each half independently, identical data)
    float s1 = a0 + a1 + a2 + a3;
    float s2 = a0 * a0 + a1 * a1 + a2 * a2 + a3 * a3;
#pragma unroll
    for (int mk = 1; mk <= 16; mk <<= 1) {
        s1 += __shfl_xor(s1, mk, 64);
        s2 += __shfl_xor(s2, mk, 64);
    }
    float mean = s1 * (1.0f / 128.0f);
    float var  = s2 * (1.0f / 128.0f) - mean * mean;
    float rr   = rsqrtf(var + 1e-5f);
    float4 gg = ((const float4*)g)[sub];
    float4 bb = ((const float4*)be)[sub];
    float r0 = (a0 - mean) * rr * gg.x + bb.x;
    float r1 = (a1 - mean) * rr * gg.y + bb.y;
    float r2 = (a2 - mean) * rr * gg.z + bb.z;
    float r3 = (a3 - mean) * rr * gg.w + bb.w;
    r0 = r0 > 0.0f ? r0 : expm1f(r0);
    r1 = r1 > 0.0f ? r1 : expm1f(r1);
    r2 = r2 > 0.0f ? r2 : expm1f(r2);
    r3 = r3 > 0.0f ? r3 : expm1f(r3);
    if (xin) {
        uint2 xi = *(const uint2*)(xin + (size_t)node * DIM + sub * 4);
        r0 += bf_lo(xi.x);
        r1 += bf_hi(xi.x);
        r2 += bf_lo(xi.y);
        r3 += bf_hi(xi.y);
    }
    if (half == 0) {
        uint2 o;
        o.x = pack_bf2(r0, r1);
        o.y = pack_bf2(r2, r3);
        *(uint2*)(outb + (size_t)node * DIM + sub * 4) = o;
    }
}

// ---------------------------------------------------------------- MFMA classifier, bf16 input: out = X @ Wc + bc
__global__ __launch_bounds__(256) void classifier_mfma(const unsigned short* __restrict__ Xb,
                                                       const unsigned short* __restrict__ Wcsw,
                                                       const float* __restrict__ bc,
                                                       float* __restrict__ out) {
    const int lane  = threadIdx.x & 63;
    const int wave  = threadIdx.x >> 6;
    const int row0w = blockIdx.x * 64 + wave * 16;
    const int m = lane & 15;
    const int q = lane >> 4;

    bf16x8 wf[12];
#pragma unroll
    for (int f = 0; f < 12; ++f)
        wf[f] = *(const bf16x8*)(Wcsw + (f << 9) + lane * 8);

    int r = row0w + m;
    if (r >= N_NODES) r = N_NODES - 1;
    const unsigned short* xp = Xb + (size_t)r * DIM + q * 8;
    bf16x8 af[4];
#pragma unroll
    for (int s = 0; s < 4; ++s) af[s] = *(const bf16x8*)(xp + s * 32);

    f32x4 acc[3];
    f32x4 z = {0.f, 0.f, 0.f, 0.f};
#pragma unroll
    for (int n = 0; n < 3; ++n) acc[n] = z;

#pragma unroll
    for (int s = 0; s < 4; ++s)
#pragma unroll
        for (int n = 0; n < 3; ++n)
            acc[n] = __builtin_amdgcn_mfma_f32_16x16x32_bf16(af[s], wf[n * 4 + s], acc[n], 0, 0, 0);

    float bcv[3];
#pragma unroll
    for (int n = 0; n < 3; ++n) {
        int c = 3 * m + n;
        bcv[n] = (c < NCLS) ? bc[c] : 0.f;
    }

#pragma unroll
    for (int j = 0; j < 4; ++j) {
        int row = row0w + q * 4 + j;
        if (row < N_NODES) {
#pragma unroll
            for (int n = 0; n < 3; ++n) {
                int c = 3 * m + n;
                if (c < NCLS)
                    out[(size_t)row * NCLS + c] = acc[n][j] + bcv[n];
            }
        }
    }
}

// ---------------------------------------------------------------- launch
extern "C" void kernel_launch(void* const* d_in, const int* in_sizes, int n_in,
                              void* d_out, int out_size, void* d_ws, size_t ws_size,
                              hipStream_t stream) {
    const float* x  = (const float*)d_in[0];
    const int*   ei = (const int*)d_in[1];
    const float* W[3]  = {(const float*)d_in[2], (const float*)d_in[6], (const float*)d_in[10]};
    const float* b[3]  = {(const float*)d_in[3], (const float*)d_in[7], (const float*)d_in[11]};
    const float* g[3]  = {(const float*)d_in[4], (const float*)d_in[8], (const float*)d_in[12]};
    const float* be[3] = {(const float*)d_in[5], (const float*)d_in[9], (const float*)d_in[13]};
    const float* Wc = (const float*)d_in[14];
    const float* bc = (const float*)d_in[15];
    float* out = (float*)d_out;

    char* ws = (char*)d_ws;
    const size_t NP = 400128;  // padded N*4 bytes
    float* dinv   = (float*)(ws);
    int*   degi   = (int*)  (ws + NP);
    int*   rowptr = (int*)  (ws + 2 * NP);
    int*   bcur   = (int*)  (ws + 3 * NP);
    int*   bsums  = (int*)  (ws + 4 * NP);
    int2*  rec    = (int2*) (ws + 4 * NP + 512);
    unsigned short* Hb = (unsigned short*)(ws + 4 * NP + 512 + (size_t)N_EDGES * 8);
    unsigned short* Ab = Hb + (size_t)N_NODES * DIM;
    unsigned short* Cb = Ab + (size_t)N_NODES * DIM;
    unsigned short* Wsw0 = Cb + (size_t)N_NODES * DIM;
    unsigned short* Wsw1 = Wsw0 + DIM * DIM;
    unsigned short* Wsw2 = Wsw1 + DIM * DIM;
    unsigned short* Wcsw = Wsw2 + DIM * DIM;   // 12*512 shorts
    int2*  tmp    = (int2*)Cb;                 // aliases Cb; dead before layer 0 writes Cb

    // ---- W pre-swizzles (bf16, MFMA B-frag order) ----
    wswz<<<64, 256, 0, stream>>>(W[0], Wsw0);
    wswz<<<64, 256, 0, stream>>>(W[1], Wsw1);
    wswz<<<64, 256, 0, stream>>>(W[2], Wsw2);
    wcswz<<<24, 256, 0, stream>>>(Wc, Wcsw);

    // ---- CSR build ----
    hipMemsetAsync(degi, 0, N_NODES * sizeof(int), stream);
    deg_count<<<(N_EDGES + 255) / 256, 256, 0, stream>>>(ei, degi);
    finalize_dinv<<<(N_NODES + 255) / 256, 256, 0, stream>>>(degi, dinv);
    scan1<<<SCAN_BLOCKS, 256, 0, stream>>>(degi, rowptr, bsums);
    scan2<<<1, 128, 0, stream>>>(bsums);
    scan3<<<SCAN_BLOCKS * 4, 256, 0, stream>>>(rowptr, bcur, bsums);
    bucket_p1<<<P1_GRID, 256, 0, stream>>>(ei, bcur, tmp);
    bucket_p2<<<NBUCK, 256, 0, stream>>>(tmp, rowptr, dinv, rec);

    const int gemm_grid = (N_NODES + 63) / 64;    // 1563
    const int agg_grid  = N_NODES / 4;            // 25000

    // layer 0: x fp32 -> Hb; agg -> Cb
    gemm_mfma_f<<<gemm_grid, 256, 0, stream>>>(x, Wsw0, Hb);
    agg_ln<<<agg_grid, 256, 0, stream>>>(Hb, nullptr, dinv, b[0], g[0], be[0], rowptr, rec, Cb);

    // layer 1: Cb -> Hb; agg (+resid Cb) -> Ab
    gemm_mfma_b<<<gemm_grid, 256, 0, stream>>>(Cb, Wsw1, Hb);
    agg_ln<<<agg_grid, 256, 0, stream>>>(Hb, Cb, dinv, b[1], g[1], be[1], rowptr, rec, Ab);

    // layer 2: Ab -> Hb; agg (+resid Ab) -> Cb
    gemm_mfma_b<<<gemm_grid, 256, 0, stream>>>(Ab, Wsw2, Hb);
    agg_ln<<<agg_grid, 256, 0, stream>>>(Hb, Ab, dinv, b[2], g[2], be[2], rowptr, rec, Cb);

    classifier_mfma<<<gemm_grid, 256, 0, stream>>>(Cb, Wcsw, bc, out);
}